// Round 14
// baseline (2022.364 us; speedup 1.0000x reference)
//
#include <hip/hip_runtime.h>
#include <hip/hip_bf16.h>

#define EPS_LN 1e-5f

// ===========================================================================
// R14 = R5 pipeline (3x-verified self-consistent) with FLOAT32 output stores.
// Unifying diagnosis: d_out is f32 (reference output dtype); all previous
// rounds stored bf16 halfwords into it, which the f32-reading checker saw as
// pair-packed garbage (decorrelated, err~0.19) or denormals~0 (probe rounds,
// err=0.1357 zeros signature). Values were right; store width was wrong.
// ===========================================================================

__global__ void count_kernel(const int* __restrict__ col, int* __restrict__ cnt, int E) {
    int i = blockIdx.x * 256 + threadIdx.x;
    if (i < E) atomicAdd(&cnt[col[i]], 1);
}

__global__ __launch_bounds__(256) void scan_kernel(const int* __restrict__ cnt,
                                                   int* __restrict__ rowPtr,
                                                   int* __restrict__ cursor,
                                                   float* __restrict__ dinv, int n) {
    __shared__ int part[257];
    int t = threadIdx.x;
    int chunk = (n + 255) >> 8;
    int s0 = t * chunk;
    int s1 = s0 + chunk; if (s1 > n) s1 = n;
    int sum = 0;
    for (int i = s0; i < s1; i++) sum += cnt[i];
    part[t] = sum;
    __syncthreads();
    if (t == 0) {
        int run = 0;
        for (int i = 0; i < 256; i++) { int v = part[i]; part[i] = run; run += v; }
        part[256] = run;
    }
    __syncthreads();
    int run = part[t];
    for (int i = s0; i < s1; i++) {
        rowPtr[i] = run;
        cursor[i] = run;
        int c = cnt[i];
        dinv[i] = rsqrtf((float)c + 1.0f);   // +1 self-loop
        run += c;
    }
    if (t == 0) rowPtr[n] = part[256];
}

__global__ void fill_kernel(const int* __restrict__ row, const int* __restrict__ col,
                            int* __restrict__ cursor, int* __restrict__ srcList, int E) {
    int i = blockIdx.x * 256 + threadIdx.x;
    if (i < E) {
        int pos = atomicAdd(&cursor[col[i]], 1);
        srcList[pos] = row[i];
    }
}

__global__ __launch_bounds__(256) void ngemm(const float* __restrict__ A,
                                             const float* __restrict__ W,
                                             const float* __restrict__ bias,
                                             float* __restrict__ C, int n, int addb) {
    int idx = blockIdx.x * 256 + threadIdx.x;
    if (idx >= n * 128) return;
    int r = idx >> 7;
    int j = idx & 127;
    float acc = addb ? bias[j] : 0.0f;
    const float* Ar = A + (size_t)r * 128;
    for (int k = 0; k < 128; k++) acc += Ar[k] * W[k * 128 + j];
    C[idx] = acc;
}

__global__ __launch_bounds__(256) void nagg(const float* __restrict__ h,
                                            const int* __restrict__ rowPtr,
                                            const int* __restrict__ srcList,
                                            const float* __restrict__ dinv,
                                            const float* __restrict__ b,
                                            float* __restrict__ out, int n) {
    int idx = blockIdx.x * 256 + threadIdx.x;
    if (idx >= n * 128) return;
    int c = idx >> 7;
    int f = idx & 127;
    float dc = dinv[c];
    float acc = h[(size_t)c * 128 + f] * dc * dc;   // self loop
    int e0 = rowPtr[c], e1 = rowPtr[c + 1];
    for (int e = e0; e < e1; e++) {
        int r = srcList[e];
        acc += h[(size_t)r * 128 + f] * dinv[r] * dc;
    }
    out[idx] = fmaxf(acc + b[f], 0.0f);
}

__global__ __launch_bounds__(256) void nln(float* __restrict__ x,
                                           const float* __restrict__ g,
                                           const float* __restrict__ beta, int n) {
    int i = blockIdx.x * 256 + threadIdx.x;
    if (i >= n) return;
    float* xi = x + (size_t)i * 128;
    float mu = 0.0f;
    for (int f = 0; f < 128; f++) mu += xi[f];
    mu *= (1.0f / 128.0f);
    float var = 0.0f;
    for (int f = 0; f < 128; f++) { float d = xi[f] - mu; var += d * d; }
    var *= (1.0f / 128.0f);
    float rs = rsqrtf(var + EPS_LN);
    for (int f = 0; f < 128; f++) xi[f] = (xi[f] - mu) * rs * g[f] + beta[f];
}

// --------------------------------------------------------------------------
// Head with FLOAT32 stores, [n,3] row-major (reference layout).
// --------------------------------------------------------------------------
__global__ __launch_bounds__(256) void nhead_f32(const float* __restrict__ hp,
                                                 const float* __restrict__ W,
                                                 const float* __restrict__ b,
                                                 float* __restrict__ out, int n) {
    int i = blockIdx.x * 256 + threadIdx.x;
    if (i >= n) return;
    float p0 = b[0], p1 = b[1], p2 = b[2];
    const float* h = hp + (size_t)i * 128;
    for (int k = 0; k < 128; k++) {
        float v = h[k];
        p0 += v * W[k * 3 + 0];
        p1 += v * W[k * 3 + 1];
        p2 += v * W[k * 3 + 2];
    }
    out[(size_t)i * 3 + 0] = p0;
    out[(size_t)i * 3 + 1] = p1;
    out[(size_t)i * 3 + 2] = p2;
}

// ---------------------------------------------------------------------------
extern "C" void kernel_launch(void* const* d_in, const int* in_sizes, int n_in,
                              void* d_out, int out_size, void* d_ws, size_t ws_size,
                              hipStream_t stream) {
    const float* x   = (const float*)d_in[0];
    const int* ei    = (const int*)d_in[1];
    const float* W1  = (const float*)d_in[2];
    const float* b1  = (const float*)d_in[3];
    const float* W2  = (const float*)d_in[4];
    const float* b2  = (const float*)d_in[5];
    const float* W3  = (const float*)d_in[6];
    const float* b3  = (const float*)d_in[7];
    const float* g1  = (const float*)d_in[8];
    const float* be1 = (const float*)d_in[9];
    const float* g2  = (const float*)d_in[10];
    const float* be2 = (const float*)d_in[11];
    const float* Wp1 = (const float*)d_in[12];
    const float* bp1 = (const float*)d_in[13];
    const float* Wp2 = (const float*)d_in[14];
    const float* bp2 = (const float*)d_in[15];
    float* out = (float*)d_out;        // f32 output (reference dtype)

    const int n = in_sizes[0] / 128;   // 50000
    const int E = in_sizes[1] / 2;     // 1600000
    const int* row = ei;               // source
    const int* col = ei + E;           // target

    char* ws = (char*)d_ws;
    size_t nA  = ((size_t)n * 4 + 255) & ~(size_t)255;
    size_t nA1 = ((size_t)(n + 1) * 4 + 255) & ~(size_t)255;
    size_t eA  = ((size_t)E * 4 + 255) & ~(size_t)255;
    int*   cnt     = (int*)ws;
    int*   rowPtr  = (int*)(ws + nA);
    int*   cursor  = (int*)(ws + nA + nA1);
    float* dinvp   = (float*)(ws + 2 * nA + nA1);
    int*   srcList = (int*)(ws + 3 * nA + nA1);
    float* bufA    = (float*)(ws + 3 * nA + nA1 + eA);
    float* bufB    = bufA + (size_t)n * 128;

    const int elemBlocks = (n * 128 + 255) / 256;
    const int edgeBlocks = (E + 255) / 256;
    const int nodeBlocks = (n + 255) / 256;

    // CSR build
    hipMemsetAsync(cnt, 0, (size_t)n * 4, stream);
    count_kernel<<<edgeBlocks, 256, 0, stream>>>(col, cnt, E);
    scan_kernel<<<1, 256, 0, stream>>>(cnt, rowPtr, cursor, dinvp, n);
    fill_kernel<<<edgeBlocks, 256, 0, stream>>>(row, col, cursor, srcList, E);

    // ---- layer 1 ----
    ngemm<<<elemBlocks, 256, 0, stream>>>(x, W1, b1, bufA, n, 0);
    nagg<<<elemBlocks, 256, 0, stream>>>(bufA, rowPtr, srcList, dinvp, b1, bufB, n);
    nln<<<nodeBlocks, 256, 0, stream>>>(bufB, g1, be1, n);
    // ---- layer 2 ----
    ngemm<<<elemBlocks, 256, 0, stream>>>(bufB, W2, b2, bufA, n, 0);
    nagg<<<elemBlocks, 256, 0, stream>>>(bufA, rowPtr, srcList, dinvp, b2, bufB, n);
    nln<<<nodeBlocks, 256, 0, stream>>>(bufB, g2, be2, n);
    // ---- layer 3 (relu, no LN) ----
    ngemm<<<elemBlocks, 256, 0, stream>>>(bufB, W3, b3, bufA, n, 0);
    nagg<<<elemBlocks, 256, 0, stream>>>(bufA, rowPtr, srcList, dinvp, b3, bufB, n);
    // ---- MLP head, f32 [n,3] output ----
    ngemm<<<elemBlocks, 256, 0, stream>>>(bufB, Wp1, bp1, bufA, n, 1);
    nhead_f32<<<nodeBlocks, 256, 0, stream>>>(bufA, Wp2, bp2, out, n);
}

// Round 15
// 888.487 us; speedup vs baseline: 2.2762x; 2.2762x over previous
//
#include <hip/hip_runtime.h>
#include <hip/hip_bf16.h>

#define EPS_LN 1e-5f

// ===========================================================================
// R15: first optimization pass on the verified R14 pipeline.
//  - ngemm -> tiled LDS GEMM (same sequential-k accumulation order)
//  - nagg+nln -> fused wave-per-node gather with x4 unrolled edge loop
// ===========================================================================

__global__ void count_kernel(const int* __restrict__ col, int* __restrict__ cnt, int E) {
    int i = blockIdx.x * 256 + threadIdx.x;
    if (i < E) atomicAdd(&cnt[col[i]], 1);
}

__global__ __launch_bounds__(256) void scan_kernel(const int* __restrict__ cnt,
                                                   int* __restrict__ rowPtr,
                                                   int* __restrict__ cursor,
                                                   float* __restrict__ dinv, int n) {
    __shared__ int part[257];
    int t = threadIdx.x;
    int chunk = (n + 255) >> 8;
    int s0 = t * chunk;
    int s1 = s0 + chunk; if (s1 > n) s1 = n;
    int sum = 0;
    for (int i = s0; i < s1; i++) sum += cnt[i];
    part[t] = sum;
    __syncthreads();
    if (t == 0) {
        int run = 0;
        for (int i = 0; i < 256; i++) { int v = part[i]; part[i] = run; run += v; }
        part[256] = run;
    }
    __syncthreads();
    int run = part[t];
    for (int i = s0; i < s1; i++) {
        rowPtr[i] = run;
        cursor[i] = run;
        int c = cnt[i];
        dinv[i] = rsqrtf((float)c + 1.0f);   // +1 self-loop
        run += c;
    }
    if (t == 0) rowPtr[n] = part[256];
}

__global__ void fill_kernel(const int* __restrict__ row, const int* __restrict__ col,
                            int* __restrict__ cursor, int* __restrict__ srcList, int E) {
    int i = blockIdx.x * 256 + threadIdx.x;
    if (i < E) {
        int pos = atomicAdd(&cursor[col[i]], 1);
        srcList[pos] = row[i];
    }
}

// ---------------------------------------------------------------------------
// Tiled GEMM: C[n,128] = A[n,128] @ W[128,128] + bias.
// block=256, tile 64 rows x 128 cols, thread tile 8x4, k staged 16 at a time.
// Same sequential-k product order as the verified naive ngemm.
// ---------------------------------------------------------------------------
__global__ __launch_bounds__(256) void gemm_nk(const float* __restrict__ A,
                                               const float* __restrict__ W,
                                               const float* __restrict__ bias,
                                               float* __restrict__ C, int n, int addb) {
    __shared__ float As[64][17];
    __shared__ float Ws[16][128];

    const int tx = threadIdx.x;
    const int row0 = blockIdx.x * 64;
    const int jg = (tx & 31) * 4;
    const int ig = (tx >> 5) * 8;

    float acc[8][4];
#pragma unroll
    for (int r = 0; r < 8; r++)
#pragma unroll
        for (int c = 0; c < 4; c++) acc[r][c] = 0.f;

    for (int k0 = 0; k0 < 128; k0 += 16) {
        {   // stage A tile (64x16)
            int r = tx >> 2;
            int cc = (tx & 3) * 4;
            int grow = row0 + r;
            float4 v = make_float4(0.f, 0.f, 0.f, 0.f);
            if (grow < n) v = *(const float4*)(A + (size_t)grow * 128 + k0 + cc);
            As[r][cc + 0] = v.x; As[r][cc + 1] = v.y;
            As[r][cc + 2] = v.z; As[r][cc + 3] = v.w;
        }
        {   // stage W chunk (16x128)
            int idx = tx * 8;
            int kr = idx >> 7;
            int jc = idx & 127;
            const float* Wp = W + (size_t)(k0 + kr) * 128 + jc;
            *(float4*)&Ws[kr][jc]     = *(const float4*)(Wp);
            *(float4*)&Ws[kr][jc + 4] = *(const float4*)(Wp + 4);
        }
        __syncthreads();
#pragma unroll
        for (int kk = 0; kk < 16; kk++) {
            float4 w = *(const float4*)&Ws[kk][jg];
#pragma unroll
            for (int r = 0; r < 8; r++) {
                float a = As[ig + r][kk];
                acc[r][0] += a * w.x;
                acc[r][1] += a * w.y;
                acc[r][2] += a * w.z;
                acc[r][3] += a * w.w;
            }
        }
        __syncthreads();
    }

    float4 bv = make_float4(0.f, 0.f, 0.f, 0.f);
    if (addb) bv = *(const float4*)(bias + jg);
#pragma unroll
    for (int r = 0; r < 8; r++) {
        int grow = row0 + ig + r;
        if (grow < n) {
            float4 v = make_float4(acc[r][0] + bv.x, acc[r][1] + bv.y,
                                   acc[r][2] + bv.z, acc[r][3] + bv.w);
            *(float4*)(C + (size_t)grow * 128 + jg) = v;
        }
    }
}

// ---------------------------------------------------------------------------
// Fused gather + self-loop + bias + relu (+ LayerNorm).
// One wave per node (e0/e1 wave-uniform -> zero divergence); float2 per lane;
// edge loop unrolled x4 with hoisted loads for memory-level parallelism.
// ---------------------------------------------------------------------------
template<bool DO_LN>
__global__ __launch_bounds__(256) void agg_post(const float* __restrict__ h,
                                                const int* __restrict__ rowPtr,
                                                const int* __restrict__ srcList,
                                                const float* __restrict__ dinv,
                                                const float* __restrict__ b,
                                                const float* __restrict__ g,
                                                const float* __restrict__ beta,
                                                float* __restrict__ out, int n) {
    int wid = (blockIdx.x * 256 + threadIdx.x) >> 6;
    int lane = threadIdx.x & 63;
    if (wid >= n) return;
    int e0 = rowPtr[wid], e1 = rowPtr[wid + 1];
    float dc = dinv[wid];
    size_t base = (size_t)wid * 128 + lane * 2;
    float2 hs = *(const float2*)(h + base);
    float ax = hs.x * dc * dc;           // self loop first (R5 order)
    float ay = hs.y * dc * dc;

    int e = e0;
    for (; e + 4 <= e1; e += 4) {
        int r0 = srcList[e + 0], r1 = srcList[e + 1];
        int r2 = srcList[e + 2], r3 = srcList[e + 3];
        float w0 = dinv[r0] * dc, w1 = dinv[r1] * dc;
        float w2 = dinv[r2] * dc, w3 = dinv[r3] * dc;
        float2 v0 = *(const float2*)(h + (size_t)r0 * 128 + lane * 2);
        float2 v1 = *(const float2*)(h + (size_t)r1 * 128 + lane * 2);
        float2 v2 = *(const float2*)(h + (size_t)r2 * 128 + lane * 2);
        float2 v3 = *(const float2*)(h + (size_t)r3 * 128 + lane * 2);
        ax += v0.x * w0; ay += v0.y * w0;
        ax += v1.x * w1; ay += v1.y * w1;
        ax += v2.x * w2; ay += v2.y * w2;
        ax += v3.x * w3; ay += v3.y * w3;
    }
    for (; e < e1; e++) {
        int r = srcList[e];
        float w = dinv[r] * dc;
        float2 v = *(const float2*)(h + (size_t)r * 128 + lane * 2);
        ax += v.x * w; ay += v.y * w;
    }

    ax = fmaxf(ax + b[lane * 2 + 0], 0.f);
    ay = fmaxf(ay + b[lane * 2 + 1], 0.f);
    if (DO_LN) {
        float s = ax + ay;
#pragma unroll
        for (int m = 32; m >= 1; m >>= 1) s += __shfl_xor(s, m, 64);
        float mu = s * (1.f / 128.f);
        float dx = ax - mu, dy = ay - mu;
        float sq = dx * dx + dy * dy;
#pragma unroll
        for (int m = 32; m >= 1; m >>= 1) sq += __shfl_xor(sq, m, 64);
        float rs = rsqrtf(sq * (1.f / 128.f) + EPS_LN);
        ax = dx * rs * g[lane * 2 + 0] + beta[lane * 2 + 0];
        ay = dy * rs * g[lane * 2 + 1] + beta[lane * 2 + 1];
    }
    *(float2*)(out + base) = make_float2(ax, ay);
}

// ---------------------------------------------------------------------------
// Head: out[i,c] = sum_k hp[i,k]*Wp2[k,c] + b[c], f32 [n,3] output.
// ---------------------------------------------------------------------------
__global__ __launch_bounds__(256) void nhead_f32(const float* __restrict__ hp,
                                                 const float* __restrict__ W,
                                                 const float* __restrict__ b,
                                                 float* __restrict__ out, int n) {
    int i = blockIdx.x * 256 + threadIdx.x;
    if (i >= n) return;
    float p0 = b[0], p1 = b[1], p2 = b[2];
    const float* h = hp + (size_t)i * 128;
    for (int k = 0; k < 128; k++) {
        float v = h[k];
        p0 += v * W[k * 3 + 0];
        p1 += v * W[k * 3 + 1];
        p2 += v * W[k * 3 + 2];
    }
    out[(size_t)i * 3 + 0] = p0;
    out[(size_t)i * 3 + 1] = p1;
    out[(size_t)i * 3 + 2] = p2;
}

// ---------------------------------------------------------------------------
extern "C" void kernel_launch(void* const* d_in, const int* in_sizes, int n_in,
                              void* d_out, int out_size, void* d_ws, size_t ws_size,
                              hipStream_t stream) {
    const float* x   = (const float*)d_in[0];
    const int* ei    = (const int*)d_in[1];
    const float* W1  = (const float*)d_in[2];
    const float* b1  = (const float*)d_in[3];
    const float* W2  = (const float*)d_in[4];
    const float* b2  = (const float*)d_in[5];
    const float* W3  = (const float*)d_in[6];
    const float* b3  = (const float*)d_in[7];
    const float* g1  = (const float*)d_in[8];
    const float* be1 = (const float*)d_in[9];
    const float* g2  = (const float*)d_in[10];
    const float* be2 = (const float*)d_in[11];
    const float* Wp1 = (const float*)d_in[12];
    const float* bp1 = (const float*)d_in[13];
    const float* Wp2 = (const float*)d_in[14];
    const float* bp2 = (const float*)d_in[15];
    float* out = (float*)d_out;

    const int n = in_sizes[0] / 128;   // 50000
    const int E = in_sizes[1] / 2;     // 1600000
    const int* row = ei;               // source
    const int* col = ei + E;           // target

    char* ws = (char*)d_ws;
    size_t nA  = ((size_t)n * 4 + 255) & ~(size_t)255;
    size_t nA1 = ((size_t)(n + 1) * 4 + 255) & ~(size_t)255;
    size_t eA  = ((size_t)E * 4 + 255) & ~(size_t)255;
    int*   cnt     = (int*)ws;
    int*   rowPtr  = (int*)(ws + nA);
    int*   cursor  = (int*)(ws + nA + nA1);
    float* dinvp   = (float*)(ws + 2 * nA + nA1);
    int*   srcList = (int*)(ws + 3 * nA + nA1);
    float* bufA    = (float*)(ws + 3 * nA + nA1 + eA);
    float* bufB    = bufA + (size_t)n * 128;

    const int gemmBlocks = (n + 63) / 64;
    const int edgeBlocks = (E + 255) / 256;
    const int nodeWaveBlocks = (n + 3) / 4;
    const int nodeBlocks = (n + 255) / 256;

    // CSR build
    hipMemsetAsync(cnt, 0, (size_t)n * 4, stream);
    count_kernel<<<edgeBlocks, 256, 0, stream>>>(col, cnt, E);
    scan_kernel<<<1, 256, 0, stream>>>(cnt, rowPtr, cursor, dinvp, n);
    fill_kernel<<<edgeBlocks, 256, 0, stream>>>(row, col, cursor, srcList, E);

    // ---- layer 1 ----
    gemm_nk<<<gemmBlocks, 256, 0, stream>>>(x, W1, b1, bufA, n, 0);
    agg_post<true><<<nodeWaveBlocks, 256, 0, stream>>>(bufA, rowPtr, srcList, dinvp,
                                                       b1, g1, be1, bufB, n);
    // ---- layer 2 ----
    gemm_nk<<<gemmBlocks, 256, 0, stream>>>(bufB, W2, b2, bufA, n, 0);
    agg_post<true><<<nodeWaveBlocks, 256, 0, stream>>>(bufA, rowPtr, srcList, dinvp,
                                                       b2, g2, be2, bufB, n);
    // ---- layer 3 (relu, no LN) ----
    gemm_nk<<<gemmBlocks, 256, 0, stream>>>(bufB, W3, b3, bufA, n, 0);
    agg_post<false><<<nodeWaveBlocks, 256, 0, stream>>>(bufA, rowPtr, srcList, dinvp,
                                                        b3, b3, b3, bufB, n);
    // ---- MLP head ----
    gemm_nk<<<gemmBlocks, 256, 0, stream>>>(bufB, Wp1, bp1, bufA, n, 1);
    nhead_f32<<<nodeBlocks, 256, 0, stream>>>(bufA, Wp2, bp2, out, n);
}

// Round 16
// 626.022 us; speedup vs baseline: 3.2305x; 1.4193x over previous
//
#include <hip/hip_runtime.h>
#include <hip/hip_bf16.h>

#define EPS_LN 1e-5f

// ===========================================================================
// R16: parallel 3-phase CSR scan (kills the 151us single-block scan) +
// bf16 pre-scaled gather buffer (halves agg random-gather traffic).
// ===========================================================================

__global__ void count_kernel(const int* __restrict__ col, int* __restrict__ cnt, int E) {
    int i = blockIdx.x * 256 + threadIdx.x;
    if (i < E) atomicAdd(&cnt[col[i]], 1);
}

// phase 1: per-256-chunk sums
__global__ __launch_bounds__(256) void scan_p1(const int* __restrict__ cnt,
                                               int* __restrict__ partial, int n) {
    __shared__ int s[256];
    int t = threadIdx.x;
    int i = blockIdx.x * 256 + t;
    s[t] = (i < n) ? cnt[i] : 0;
    __syncthreads();
    for (int st = 128; st > 0; st >>= 1) {
        if (t < st) s[t] += s[t + st];
        __syncthreads();
    }
    if (t == 0) partial[blockIdx.x] = s[0];
}

// phase 2: exclusive scan of block partials (nb <= ~1024), 1 block
__global__ __launch_bounds__(256) void scan_p2(int* __restrict__ partial,
                                               int* __restrict__ rowPtr,
                                               int n, int nb) {
    if (threadIdx.x == 0) {
        int run = 0;
        for (int i = 0; i < nb; i++) { int v = partial[i]; partial[i] = run; run += v; }
        rowPtr[n] = run;
    }
}

// phase 3: in-block exclusive scan + block offset -> rowPtr/cursor/dinv
__global__ __launch_bounds__(256) void scan_p3(const int* __restrict__ cnt,
                                               const int* __restrict__ partial,
                                               int* __restrict__ rowPtr,
                                               int* __restrict__ cursor,
                                               float* __restrict__ dinv, int n) {
    __shared__ int sh[256];
    int t = threadIdx.x;
    int i = blockIdx.x * 256 + t;
    int v = (i < n) ? cnt[i] : 0;
    sh[t] = v;
    __syncthreads();
    for (int d = 1; d < 256; d <<= 1) {
        int add = (t >= d) ? sh[t - d] : 0;
        __syncthreads();
        sh[t] += add;
        __syncthreads();
    }
    if (i < n) {
        int excl = sh[t] - v + partial[blockIdx.x];
        rowPtr[i] = excl;
        cursor[i] = excl;
        dinv[i] = rsqrtf((float)v + 1.0f);   // +1 self-loop
    }
}

__global__ void fill_kernel(const int* __restrict__ row, const int* __restrict__ col,
                            int* __restrict__ cursor, int* __restrict__ srcList, int E) {
    int i = blockIdx.x * 256 + threadIdx.x;
    if (i < E) {
        int pos = atomicAdd(&cursor[col[i]], 1);
        srcList[pos] = row[i];
    }
}

// ---------------------------------------------------------------------------
// Tiled GEMM + optional bf16 pre-scaled copy: Cb[r,f] = bf16(C[r,f]*dinv[r]).
// ---------------------------------------------------------------------------
__global__ __launch_bounds__(256) void gemm_nk(const float* __restrict__ A,
                                               const float* __restrict__ W,
                                               const float* __restrict__ bias,
                                               const float* __restrict__ dinv,
                                               float* __restrict__ C,
                                               unsigned short* __restrict__ Cb,
                                               int n, int addb) {
    __shared__ float As[64][17];
    __shared__ float Ws[16][128];

    const int tx = threadIdx.x;
    const int row0 = blockIdx.x * 64;
    const int jg = (tx & 31) * 4;
    const int ig = (tx >> 5) * 8;

    float acc[8][4];
#pragma unroll
    for (int r = 0; r < 8; r++)
#pragma unroll
        for (int c = 0; c < 4; c++) acc[r][c] = 0.f;

    for (int k0 = 0; k0 < 128; k0 += 16) {
        {
            int r = tx >> 2;
            int cc = (tx & 3) * 4;
            int grow = row0 + r;
            float4 v = make_float4(0.f, 0.f, 0.f, 0.f);
            if (grow < n) v = *(const float4*)(A + (size_t)grow * 128 + k0 + cc);
            As[r][cc + 0] = v.x; As[r][cc + 1] = v.y;
            As[r][cc + 2] = v.z; As[r][cc + 3] = v.w;
        }
        {
            int idx = tx * 8;
            int kr = idx >> 7;
            int jc = idx & 127;
            const float* Wp = W + (size_t)(k0 + kr) * 128 + jc;
            *(float4*)&Ws[kr][jc]     = *(const float4*)(Wp);
            *(float4*)&Ws[kr][jc + 4] = *(const float4*)(Wp + 4);
        }
        __syncthreads();
#pragma unroll
        for (int kk = 0; kk < 16; kk++) {
            float4 w = *(const float4*)&Ws[kk][jg];
#pragma unroll
            for (int r = 0; r < 8; r++) {
                float a = As[ig + r][kk];
                acc[r][0] += a * w.x;
                acc[r][1] += a * w.y;
                acc[r][2] += a * w.z;
                acc[r][3] += a * w.w;
            }
        }
        __syncthreads();
    }

    float4 bv = make_float4(0.f, 0.f, 0.f, 0.f);
    if (addb) bv = *(const float4*)(bias + jg);
#pragma unroll
    for (int r = 0; r < 8; r++) {
        int grow = row0 + ig + r;
        if (grow < n) {
            float4 v = make_float4(acc[r][0] + bv.x, acc[r][1] + bv.y,
                                   acc[r][2] + bv.z, acc[r][3] + bv.w);
            *(float4*)(C + (size_t)grow * 128 + jg) = v;
            if (Cb) {
                float dr = dinv[grow];
                __hip_bfloat16 t0 = __float2bfloat16(v.x * dr);
                __hip_bfloat16 t1 = __float2bfloat16(v.y * dr);
                __hip_bfloat16 t2 = __float2bfloat16(v.z * dr);
                __hip_bfloat16 t3 = __float2bfloat16(v.w * dr);
                ushort4 u;
                u.x = *(unsigned short*)&t0; u.y = *(unsigned short*)&t1;
                u.z = *(unsigned short*)&t2; u.w = *(unsigned short*)&t3;
                *(ushort4*)(Cb + (size_t)grow * 128 + jg) = u;
            }
        }
    }
}

// ---------------------------------------------------------------------------
// Fused gather (bf16 pre-scaled) + self-loop(f32) + bias + relu (+ LN).
// One wave per node; 1 uint per lane per edge; unroll x8.
// ---------------------------------------------------------------------------
template<bool DO_LN>
__global__ __launch_bounds__(256) void agg_post(const float* __restrict__ h,
                                                const unsigned int* __restrict__ hb,
                                                const int* __restrict__ rowPtr,
                                                const int* __restrict__ srcList,
                                                const float* __restrict__ dinv,
                                                const float* __restrict__ b,
                                                const float* __restrict__ g,
                                                const float* __restrict__ beta,
                                                float* __restrict__ out, int n) {
    int wid = (blockIdx.x * 256 + threadIdx.x) >> 6;
    int lane = threadIdx.x & 63;
    if (wid >= n) return;
    int e0 = rowPtr[wid], e1 = rowPtr[wid + 1];
    float dc = dinv[wid];
    size_t base = (size_t)wid * 128 + lane * 2;
    float2 hs = *(const float2*)(h + base);
    float ax = hs.x * dc * dc;
    float ay = hs.y * dc * dc;

    int e = e0;
    for (; e + 8 <= e1; e += 8) {
        int r0 = srcList[e + 0], r1 = srcList[e + 1];
        int r2 = srcList[e + 2], r3 = srcList[e + 3];
        int r4 = srcList[e + 4], r5 = srcList[e + 5];
        int r6 = srcList[e + 6], r7 = srcList[e + 7];
        unsigned int u0 = hb[(size_t)r0 * 64 + lane];
        unsigned int u1 = hb[(size_t)r1 * 64 + lane];
        unsigned int u2 = hb[(size_t)r2 * 64 + lane];
        unsigned int u3 = hb[(size_t)r3 * 64 + lane];
        unsigned int u4 = hb[(size_t)r4 * 64 + lane];
        unsigned int u5 = hb[(size_t)r5 * 64 + lane];
        unsigned int u6 = hb[(size_t)r6 * 64 + lane];
        unsigned int u7 = hb[(size_t)r7 * 64 + lane];
        ax += __uint_as_float(u0 << 16) * dc;  ay += __uint_as_float(u0 & 0xffff0000u) * dc;
        ax += __uint_as_float(u1 << 16) * dc;  ay += __uint_as_float(u1 & 0xffff0000u) * dc;
        ax += __uint_as_float(u2 << 16) * dc;  ay += __uint_as_float(u2 & 0xffff0000u) * dc;
        ax += __uint_as_float(u3 << 16) * dc;  ay += __uint_as_float(u3 & 0xffff0000u) * dc;
        ax += __uint_as_float(u4 << 16) * dc;  ay += __uint_as_float(u4 & 0xffff0000u) * dc;
        ax += __uint_as_float(u5 << 16) * dc;  ay += __uint_as_float(u5 & 0xffff0000u) * dc;
        ax += __uint_as_float(u6 << 16) * dc;  ay += __uint_as_float(u6 & 0xffff0000u) * dc;
        ax += __uint_as_float(u7 << 16) * dc;  ay += __uint_as_float(u7 & 0xffff0000u) * dc;
    }
    for (; e < e1; e++) {
        int r = srcList[e];
        unsigned int u = hb[(size_t)r * 64 + lane];
        ax += __uint_as_float(u << 16) * dc;
        ay += __uint_as_float(u & 0xffff0000u) * dc;
    }

    ax = fmaxf(ax + b[lane * 2 + 0], 0.f);
    ay = fmaxf(ay + b[lane * 2 + 1], 0.f);
    if (DO_LN) {
        float s = ax + ay;
#pragma unroll
        for (int m = 32; m >= 1; m >>= 1) s += __shfl_xor(s, m, 64);
        float mu = s * (1.f / 128.f);
        float dx = ax - mu, dy = ay - mu;
        float sq = dx * dx + dy * dy;
#pragma unroll
        for (int m = 32; m >= 1; m >>= 1) sq += __shfl_xor(sq, m, 64);
        float rs = rsqrtf(sq * (1.f / 128.f) + EPS_LN);
        ax = dx * rs * g[lane * 2 + 0] + beta[lane * 2 + 0];
        ay = dy * rs * g[lane * 2 + 1] + beta[lane * 2 + 1];
    }
    *(float2*)(out + base) = make_float2(ax, ay);
}

// ---------------------------------------------------------------------------
__global__ __launch_bounds__(256) void nhead_f32(const float* __restrict__ hp,
                                                 const float* __restrict__ W,
                                                 const float* __restrict__ b,
                                                 float* __restrict__ out, int n) {
    int i = blockIdx.x * 256 + threadIdx.x;
    if (i >= n) return;
    float p0 = b[0], p1 = b[1], p2 = b[2];
    const float* h = hp + (size_t)i * 128;
    for (int k = 0; k < 128; k++) {
        float v = h[k];
        p0 += v * W[k * 3 + 0];
        p1 += v * W[k * 3 + 1];
        p2 += v * W[k * 3 + 2];
    }
    out[(size_t)i * 3 + 0] = p0;
    out[(size_t)i * 3 + 1] = p1;
    out[(size_t)i * 3 + 2] = p2;
}

// ---------------------------------------------------------------------------
extern "C" void kernel_launch(void* const* d_in, const int* in_sizes, int n_in,
                              void* d_out, int out_size, void* d_ws, size_t ws_size,
                              hipStream_t stream) {
    const float* x   = (const float*)d_in[0];
    const int* ei    = (const int*)d_in[1];
    const float* W1  = (const float*)d_in[2];
    const float* b1  = (const float*)d_in[3];
    const float* W2  = (const float*)d_in[4];
    const float* b2  = (const float*)d_in[5];
    const float* W3  = (const float*)d_in[6];
    const float* b3  = (const float*)d_in[7];
    const float* g1  = (const float*)d_in[8];
    const float* be1 = (const float*)d_in[9];
    const float* g2  = (const float*)d_in[10];
    const float* be2 = (const float*)d_in[11];
    const float* Wp1 = (const float*)d_in[12];
    const float* bp1 = (const float*)d_in[13];
    const float* Wp2 = (const float*)d_in[14];
    const float* bp2 = (const float*)d_in[15];
    float* out = (float*)d_out;

    const int n = in_sizes[0] / 128;   // 50000
    const int E = in_sizes[1] / 2;     // 1600000
    const int* row = ei;
    const int* col = ei + E;

    char* ws = (char*)d_ws;
    size_t nA  = ((size_t)n * 4 + 255) & ~(size_t)255;
    size_t nA1 = ((size_t)(n + 1) * 4 + 255) & ~(size_t)255;
    size_t eA  = ((size_t)E * 4 + 255) & ~(size_t)255;
    size_t hbA = ((size_t)n * 128 * 2 + 255) & ~(size_t)255;
    int*   cnt     = (int*)ws;
    int*   rowPtr  = (int*)(ws + nA);
    int*   cursor  = (int*)(ws + nA + nA1);
    float* dinvp   = (float*)(ws + 2 * nA + nA1);
    int*   partial = (int*)(ws + 3 * nA + nA1);            // <=1024 ints (uses nA block)
    int*   srcList = (int*)(ws + 4 * nA + nA1);
    unsigned short* hb = (unsigned short*)(ws + 4 * nA + nA1 + eA);
    float* bufA    = (float*)(ws + 4 * nA + nA1 + eA + hbA);
    float* bufB    = bufA + (size_t)n * 128;

    const int gemmBlocks = (n + 63) / 64;
    const int edgeBlocks = (E + 255) / 256;
    const int nodeWaveBlocks = (n + 3) / 4;
    const int nodeBlocks = (n + 255) / 256;   // also #scan blocks (196)

    // CSR build (parallel scan)
    hipMemsetAsync(cnt, 0, (size_t)n * 4, stream);
    count_kernel<<<edgeBlocks, 256, 0, stream>>>(col, cnt, E);
    scan_p1<<<nodeBlocks, 256, 0, stream>>>(cnt, partial, n);
    scan_p2<<<1, 256, 0, stream>>>(partial, rowPtr, n, nodeBlocks);
    scan_p3<<<nodeBlocks, 256, 0, stream>>>(cnt, partial, rowPtr, cursor, dinvp, n);
    fill_kernel<<<edgeBlocks, 256, 0, stream>>>(row, col, cursor, srcList, E);

    // ---- layer 1 ----
    gemm_nk<<<gemmBlocks, 256, 0, stream>>>(x, W1, b1, dinvp, bufA, hb, n, 0);
    agg_post<true><<<nodeWaveBlocks, 256, 0, stream>>>(bufA, (const unsigned int*)hb,
                                                       rowPtr, srcList, dinvp,
                                                       b1, g1, be1, bufB, n);
    // ---- layer 2 ----
    gemm_nk<<<gemmBlocks, 256, 0, stream>>>(bufB, W2, b2, dinvp, bufA, hb, n, 0);
    agg_post<true><<<nodeWaveBlocks, 256, 0, stream>>>(bufA, (const unsigned int*)hb,
                                                       rowPtr, srcList, dinvp,
                                                       b2, g2, be2, bufB, n);
    // ---- layer 3 (relu, no LN) ----
    gemm_nk<<<gemmBlocks, 256, 0, stream>>>(bufB, W3, b3, dinvp, bufA, hb, n, 0);
    agg_post<false><<<nodeWaveBlocks, 256, 0, stream>>>(bufA, (const unsigned int*)hb,
                                                        rowPtr, srcList, dinvp,
                                                        b3, b3, b3, bufB, n);
    // ---- MLP head ----
    gemm_nk<<<gemmBlocks, 256, 0, stream>>>(bufB, Wp1, bp1, dinvp, bufA, nullptr, n, 1);
    nhead_f32<<<nodeBlocks, 256, 0, stream>>>(bufA, Wp2, bp2, out, n);
}

// Round 17
// 602.967 us; speedup vs baseline: 3.3540x; 1.0382x over previous
//
#include <hip/hip_runtime.h>
#include <hip/hip_bf16.h>

#define EPS_LN 1e-5f

// ===========================================================================
// R17: range-partitioned CSR fill (kills the 16x write amplification seen in
// R16: WRITE_SIZE 101MB for a 6.4MB srcList). Blocks are ordered range-major
// so the active write window stays ~1MB -> lines fill before eviction.
// ===========================================================================

__global__ void count_kernel(const int* __restrict__ col, int* __restrict__ cnt, int E) {
    int i = blockIdx.x * 256 + threadIdx.x;
    if (i < E) atomicAdd(&cnt[col[i]], 1);
}

__global__ __launch_bounds__(256) void scan_p1(const int* __restrict__ cnt,
                                               int* __restrict__ partial, int n) {
    __shared__ int s[256];
    int t = threadIdx.x;
    int i = blockIdx.x * 256 + t;
    s[t] = (i < n) ? cnt[i] : 0;
    __syncthreads();
    for (int st = 128; st > 0; st >>= 1) {
        if (t < st) s[t] += s[t + st];
        __syncthreads();
    }
    if (t == 0) partial[blockIdx.x] = s[0];
}

__global__ __launch_bounds__(256) void scan_p2(int* __restrict__ partial,
                                               int* __restrict__ rowPtr,
                                               int n, int nb) {
    if (threadIdx.x == 0) {
        int run = 0;
        for (int i = 0; i < nb; i++) { int v = partial[i]; partial[i] = run; run += v; }
        rowPtr[n] = run;
    }
}

__global__ __launch_bounds__(256) void scan_p3(const int* __restrict__ cnt,
                                               const int* __restrict__ partial,
                                               int* __restrict__ rowPtr,
                                               int* __restrict__ cursor,
                                               float* __restrict__ dinv, int n) {
    __shared__ int sh[256];
    int t = threadIdx.x;
    int i = blockIdx.x * 256 + t;
    int v = (i < n) ? cnt[i] : 0;
    sh[t] = v;
    __syncthreads();
    for (int d = 1; d < 256; d <<= 1) {
        int add = (t >= d) ? sh[t - d] : 0;
        __syncthreads();
        sh[t] += add;
        __syncthreads();
    }
    if (i < n) {
        int excl = sh[t] - v + partial[blockIdx.x];
        rowPtr[i] = excl;
        cursor[i] = excl;
        dinv[i] = rsqrtf((float)v + 1.0f);   // +1 self-loop
    }
}

// Range-partitioned fill: block b handles edge-chunk (b % chunks) filtered to
// target range (b / chunks). Range-major dispatch order keeps the active
// srcList write window small (-> line-fill before eviction).
__global__ __launch_bounds__(256) void fill_part(const int* __restrict__ row,
                                                 const int* __restrict__ col,
                                                 int* __restrict__ cursor,
                                                 int* __restrict__ srcList,
                                                 int E, int chunks, int rw) {
    int p = blockIdx.x / chunks;
    int cb = blockIdx.x - p * chunks;
    int i = cb * 256 + threadIdx.x;
    if (i >= E) return;
    int c = col[i];
    int lo = p * rw;
    if (c >= lo && c < lo + rw) {
        int pos = atomicAdd(&cursor[c], 1);
        srcList[pos] = row[i];
    }
}

// ---------------------------------------------------------------------------
// Tiled GEMM + optional bf16 pre-scaled copy: Cb[r,f] = bf16(C[r,f]*dinv[r]).
// ---------------------------------------------------------------------------
__global__ __launch_bounds__(256) void gemm_nk(const float* __restrict__ A,
                                               const float* __restrict__ W,
                                               const float* __restrict__ bias,
                                               const float* __restrict__ dinv,
                                               float* __restrict__ C,
                                               unsigned short* __restrict__ Cb,
                                               int n, int addb) {
    __shared__ float As[64][17];
    __shared__ float Ws[16][128];

    const int tx = threadIdx.x;
    const int row0 = blockIdx.x * 64;
    const int jg = (tx & 31) * 4;
    const int ig = (tx >> 5) * 8;

    float acc[8][4];
#pragma unroll
    for (int r = 0; r < 8; r++)
#pragma unroll
        for (int c = 0; c < 4; c++) acc[r][c] = 0.f;

    for (int k0 = 0; k0 < 128; k0 += 16) {
        {
            int r = tx >> 2;
            int cc = (tx & 3) * 4;
            int grow = row0 + r;
            float4 v = make_float4(0.f, 0.f, 0.f, 0.f);
            if (grow < n) v = *(const float4*)(A + (size_t)grow * 128 + k0 + cc);
            As[r][cc + 0] = v.x; As[r][cc + 1] = v.y;
            As[r][cc + 2] = v.z; As[r][cc + 3] = v.w;
        }
        {
            int idx = tx * 8;
            int kr = idx >> 7;
            int jc = idx & 127;
            const float* Wp = W + (size_t)(k0 + kr) * 128 + jc;
            *(float4*)&Ws[kr][jc]     = *(const float4*)(Wp);
            *(float4*)&Ws[kr][jc + 4] = *(const float4*)(Wp + 4);
        }
        __syncthreads();
#pragma unroll
        for (int kk = 0; kk < 16; kk++) {
            float4 w = *(const float4*)&Ws[kk][jg];
#pragma unroll
            for (int r = 0; r < 8; r++) {
                float a = As[ig + r][kk];
                acc[r][0] += a * w.x;
                acc[r][1] += a * w.y;
                acc[r][2] += a * w.z;
                acc[r][3] += a * w.w;
            }
        }
        __syncthreads();
    }

    float4 bv = make_float4(0.f, 0.f, 0.f, 0.f);
    if (addb) bv = *(const float4*)(bias + jg);
#pragma unroll
    for (int r = 0; r < 8; r++) {
        int grow = row0 + ig + r;
        if (grow < n) {
            float4 v = make_float4(acc[r][0] + bv.x, acc[r][1] + bv.y,
                                   acc[r][2] + bv.z, acc[r][3] + bv.w);
            *(float4*)(C + (size_t)grow * 128 + jg) = v;
            if (Cb) {
                float dr = dinv[grow];
                __hip_bfloat16 t0 = __float2bfloat16(v.x * dr);
                __hip_bfloat16 t1 = __float2bfloat16(v.y * dr);
                __hip_bfloat16 t2 = __float2bfloat16(v.z * dr);
                __hip_bfloat16 t3 = __float2bfloat16(v.w * dr);
                ushort4 u;
                u.x = *(unsigned short*)&t0; u.y = *(unsigned short*)&t1;
                u.z = *(unsigned short*)&t2; u.w = *(unsigned short*)&t3;
                *(ushort4*)(Cb + (size_t)grow * 128 + jg) = u;
            }
        }
    }
}

// ---------------------------------------------------------------------------
// Fused gather (bf16 pre-scaled) + self-loop(f32) + bias + relu (+ LN).
// ---------------------------------------------------------------------------
template<bool DO_LN>
__global__ __launch_bounds__(256) void agg_post(const float* __restrict__ h,
                                                const unsigned int* __restrict__ hb,
                                                const int* __restrict__ rowPtr,
                                                const int* __restrict__ srcList,
                                                const float* __restrict__ dinv,
                                                const float* __restrict__ b,
                                                const float* __restrict__ g,
                                                const float* __restrict__ beta,
                                                float* __restrict__ out, int n) {
    int wid = (blockIdx.x * 256 + threadIdx.x) >> 6;
    int lane = threadIdx.x & 63;
    if (wid >= n) return;
    int e0 = rowPtr[wid], e1 = rowPtr[wid + 1];
    float dc = dinv[wid];
    size_t base = (size_t)wid * 128 + lane * 2;
    float2 hs = *(const float2*)(h + base);
    float ax = hs.x * dc * dc;
    float ay = hs.y * dc * dc;

    int e = e0;
    for (; e + 8 <= e1; e += 8) {
        int r0 = srcList[e + 0], r1 = srcList[e + 1];
        int r2 = srcList[e + 2], r3 = srcList[e + 3];
        int r4 = srcList[e + 4], r5 = srcList[e + 5];
        int r6 = srcList[e + 6], r7 = srcList[e + 7];
        unsigned int u0 = hb[(size_t)r0 * 64 + lane];
        unsigned int u1 = hb[(size_t)r1 * 64 + lane];
        unsigned int u2 = hb[(size_t)r2 * 64 + lane];
        unsigned int u3 = hb[(size_t)r3 * 64 + lane];
        unsigned int u4 = hb[(size_t)r4 * 64 + lane];
        unsigned int u5 = hb[(size_t)r5 * 64 + lane];
        unsigned int u6 = hb[(size_t)r6 * 64 + lane];
        unsigned int u7 = hb[(size_t)r7 * 64 + lane];
        ax += __uint_as_float(u0 << 16) * dc;  ay += __uint_as_float(u0 & 0xffff0000u) * dc;
        ax += __uint_as_float(u1 << 16) * dc;  ay += __uint_as_float(u1 & 0xffff0000u) * dc;
        ax += __uint_as_float(u2 << 16) * dc;  ay += __uint_as_float(u2 & 0xffff0000u) * dc;
        ax += __uint_as_float(u3 << 16) * dc;  ay += __uint_as_float(u3 & 0xffff0000u) * dc;
        ax += __uint_as_float(u4 << 16) * dc;  ay += __uint_as_float(u4 & 0xffff0000u) * dc;
        ax += __uint_as_float(u5 << 16) * dc;  ay += __uint_as_float(u5 & 0xffff0000u) * dc;
        ax += __uint_as_float(u6 << 16) * dc;  ay += __uint_as_float(u6 & 0xffff0000u) * dc;
        ax += __uint_as_float(u7 << 16) * dc;  ay += __uint_as_float(u7 & 0xffff0000u) * dc;
    }
    for (; e < e1; e++) {
        int r = srcList[e];
        unsigned int u = hb[(size_t)r * 64 + lane];
        ax += __uint_as_float(u << 16) * dc;
        ay += __uint_as_float(u & 0xffff0000u) * dc;
    }

    ax = fmaxf(ax + b[lane * 2 + 0], 0.f);
    ay = fmaxf(ay + b[lane * 2 + 1], 0.f);
    if (DO_LN) {
        float s = ax + ay;
#pragma unroll
        for (int m = 32; m >= 1; m >>= 1) s += __shfl_xor(s, m, 64);
        float mu = s * (1.f / 128.f);
        float dx = ax - mu, dy = ay - mu;
        float sq = dx * dx + dy * dy;
#pragma unroll
        for (int m = 32; m >= 1; m >>= 1) sq += __shfl_xor(sq, m, 64);
        float rs = rsqrtf(sq * (1.f / 128.f) + EPS_LN);
        ax = dx * rs * g[lane * 2 + 0] + beta[lane * 2 + 0];
        ay = dy * rs * g[lane * 2 + 1] + beta[lane * 2 + 1];
    }
    *(float2*)(out + base) = make_float2(ax, ay);
}

// ---------------------------------------------------------------------------
__global__ __launch_bounds__(256) void nhead_f32(const float* __restrict__ hp,
                                                 const float* __restrict__ W,
                                                 const float* __restrict__ b,
                                                 float* __restrict__ out, int n) {
    int i = blockIdx.x * 256 + threadIdx.x;
    if (i >= n) return;
    float p0 = b[0], p1 = b[1], p2 = b[2];
    const float* h = hp + (size_t)i * 128;
    for (int k = 0; k < 128; k++) {
        float v = h[k];
        p0 += v * W[k * 3 + 0];
        p1 += v * W[k * 3 + 1];
        p2 += v * W[k * 3 + 2];
    }
    out[(size_t)i * 3 + 0] = p0;
    out[(size_t)i * 3 + 1] = p1;
    out[(size_t)i * 3 + 2] = p2;
}

// ---------------------------------------------------------------------------
extern "C" void kernel_launch(void* const* d_in, const int* in_sizes, int n_in,
                              void* d_out, int out_size, void* d_ws, size_t ws_size,
                              hipStream_t stream) {
    const float* x   = (const float*)d_in[0];
    const int* ei    = (const int*)d_in[1];
    const float* W1  = (const float*)d_in[2];
    const float* b1  = (const float*)d_in[3];
    const float* W2  = (const float*)d_in[4];
    const float* b2  = (const float*)d_in[5];
    const float* W3  = (const float*)d_in[6];
    const float* b3  = (const float*)d_in[7];
    const float* g1  = (const float*)d_in[8];
    const float* be1 = (const float*)d_in[9];
    const float* g2  = (const float*)d_in[10];
    const float* be2 = (const float*)d_in[11];
    const float* Wp1 = (const float*)d_in[12];
    const float* bp1 = (const float*)d_in[13];
    const float* Wp2 = (const float*)d_in[14];
    const float* bp2 = (const float*)d_in[15];
    float* out = (float*)d_out;

    const int n = in_sizes[0] / 128;   // 50000
    const int E = in_sizes[1] / 2;     // 1600000
    const int* row = ei;
    const int* col = ei + E;

    char* ws = (char*)d_ws;
    size_t nA  = ((size_t)n * 4 + 255) & ~(size_t)255;
    size_t nA1 = ((size_t)(n + 1) * 4 + 255) & ~(size_t)255;
    size_t eA  = ((size_t)E * 4 + 255) & ~(size_t)255;
    size_t hbA = ((size_t)n * 128 * 2 + 255) & ~(size_t)255;
    int*   cnt     = (int*)ws;
    int*   rowPtr  = (int*)(ws + nA);
    int*   cursor  = (int*)(ws + nA + nA1);
    float* dinvp   = (float*)(ws + 2 * nA + nA1);
    int*   partial = (int*)(ws + 3 * nA + nA1);
    int*   srcList = (int*)(ws + 4 * nA + nA1);
    unsigned short* hb = (unsigned short*)(ws + 4 * nA + nA1 + eA);
    float* bufA    = (float*)(ws + 4 * nA + nA1 + eA + hbA);
    float* bufB    = bufA + (size_t)n * 128;

    const int gemmBlocks = (n + 63) / 64;
    const int edgeBlocks = (E + 255) / 256;
    const int nodeWaveBlocks = (n + 3) / 4;
    const int nodeBlocks = (n + 255) / 256;

    const int P = 8;                      // target-range partitions for fill
    const int rw = (n + P - 1) / P;       // 6250 nodes per range

    // CSR build
    hipMemsetAsync(cnt, 0, (size_t)n * 4, stream);
    count_kernel<<<edgeBlocks, 256, 0, stream>>>(col, cnt, E);
    scan_p1<<<nodeBlocks, 256, 0, stream>>>(cnt, partial, n);
    scan_p2<<<1, 256, 0, stream>>>(partial, rowPtr, n, nodeBlocks);
    scan_p3<<<nodeBlocks, 256, 0, stream>>>(cnt, partial, rowPtr, cursor, dinvp, n);
    fill_part<<<P * edgeBlocks, 256, 0, stream>>>(row, col, cursor, srcList, E,
                                                  edgeBlocks, rw);

    // ---- layer 1 ----
    gemm_nk<<<gemmBlocks, 256, 0, stream>>>(x, W1, b1, dinvp, bufA, hb, n, 0);
    agg_post<true><<<nodeWaveBlocks, 256, 0, stream>>>(bufA, (const unsigned int*)hb,
                                                       rowPtr, srcList, dinvp,
                                                       b1, g1, be1, bufB, n);
    // ---- layer 2 ----
    gemm_nk<<<gemmBlocks, 256, 0, stream>>>(bufB, W2, b2, dinvp, bufA, hb, n, 0);
    agg_post<true><<<nodeWaveBlocks, 256, 0, stream>>>(bufA, (const unsigned int*)hb,
                                                       rowPtr, srcList, dinvp,
                                                       b2, g2, be2, bufB, n);
    // ---- layer 3 (relu, no LN) ----
    gemm_nk<<<gemmBlocks, 256, 0, stream>>>(bufB, W3, b3, dinvp, bufA, hb, n, 0);
    agg_post<false><<<nodeWaveBlocks, 256, 0, stream>>>(bufA, (const unsigned int*)hb,
                                                        rowPtr, srcList, dinvp,
                                                        b3, b3, b3, bufB, n);
    // ---- MLP head ----
    gemm_nk<<<gemmBlocks, 256, 0, stream>>>(bufB, Wp1, bp1, dinvp, bufA, nullptr, n, 1);
    nhead_f32<<<nodeBlocks, 256, 0, stream>>>(bufA, Wp2, bp2, out, n);
}

// Round 18
// 598.001 us; speedup vs baseline: 3.3819x; 1.0083x over previous
//
#include <hip/hip_runtime.h>
#include <hip/hip_bf16.h>

#define EPS_LN 1e-5f

// ===========================================================================
// R18: GEMM upgraded to 128x128 block tile / 8x8 thread tile (64 FMA per 10
// LDS reads vs 32/12 before). Same sequential-k accumulation order ->
// bitwise-identical results. Everything else unchanged from R17.
// ===========================================================================

__global__ void count_kernel(const int* __restrict__ col, int* __restrict__ cnt, int E) {
    int i = blockIdx.x * 256 + threadIdx.x;
    if (i < E) atomicAdd(&cnt[col[i]], 1);
}

__global__ __launch_bounds__(256) void scan_p1(const int* __restrict__ cnt,
                                               int* __restrict__ partial, int n) {
    __shared__ int s[256];
    int t = threadIdx.x;
    int i = blockIdx.x * 256 + t;
    s[t] = (i < n) ? cnt[i] : 0;
    __syncthreads();
    for (int st = 128; st > 0; st >>= 1) {
        if (t < st) s[t] += s[t + st];
        __syncthreads();
    }
    if (t == 0) partial[blockIdx.x] = s[0];
}

__global__ __launch_bounds__(256) void scan_p2(int* __restrict__ partial,
                                               int* __restrict__ rowPtr,
                                               int n, int nb) {
    if (threadIdx.x == 0) {
        int run = 0;
        for (int i = 0; i < nb; i++) { int v = partial[i]; partial[i] = run; run += v; }
        rowPtr[n] = run;
    }
}

__global__ __launch_bounds__(256) void scan_p3(const int* __restrict__ cnt,
                                               const int* __restrict__ partial,
                                               int* __restrict__ rowPtr,
                                               int* __restrict__ cursor,
                                               float* __restrict__ dinv, int n) {
    __shared__ int sh[256];
    int t = threadIdx.x;
    int i = blockIdx.x * 256 + t;
    int v = (i < n) ? cnt[i] : 0;
    sh[t] = v;
    __syncthreads();
    for (int d = 1; d < 256; d <<= 1) {
        int add = (t >= d) ? sh[t - d] : 0;
        __syncthreads();
        sh[t] += add;
        __syncthreads();
    }
    if (i < n) {
        int excl = sh[t] - v + partial[blockIdx.x];
        rowPtr[i] = excl;
        cursor[i] = excl;
        dinv[i] = rsqrtf((float)v + 1.0f);   // +1 self-loop
    }
}

__global__ __launch_bounds__(256) void fill_part(const int* __restrict__ row,
                                                 const int* __restrict__ col,
                                                 int* __restrict__ cursor,
                                                 int* __restrict__ srcList,
                                                 int E, int chunks, int rw) {
    int p = blockIdx.x / chunks;
    int cb = blockIdx.x - p * chunks;
    int i = cb * 256 + threadIdx.x;
    if (i >= E) return;
    int c = col[i];
    int lo = p * rw;
    if (c >= lo && c < lo + rw) {
        int pos = atomicAdd(&cursor[c], 1);
        srcList[pos] = row[i];
    }
}

// ---------------------------------------------------------------------------
// Tiled GEMM: 128x128 block tile, 256 threads, 8x8 per thread, BK=16.
// Sequential-k accumulation (bitwise-identical to previous rounds).
// Optional bf16 pre-scaled copy Cb[r,f] = bf16(C[r,f]*dinv[r]).
// ---------------------------------------------------------------------------
__global__ __launch_bounds__(256) void gemm_nk(const float* __restrict__ A,
                                               const float* __restrict__ W,
                                               const float* __restrict__ bias,
                                               const float* __restrict__ dinv,
                                               float* __restrict__ C,
                                               unsigned short* __restrict__ Cb,
                                               int n, int addb) {
    __shared__ float As[128][17];    // 128 rows x 16 k (+1 pad)
    __shared__ float Ws[16][128];    // 16 k x 128 cols

    const int tx = threadIdx.x;
    const int row0 = blockIdx.x * 128;
    const int jg = (tx & 15) * 8;    // col base (0..120)
    const int ig = (tx >> 4) * 8;    // row base (0..120)

    float acc[8][8];
#pragma unroll
    for (int r = 0; r < 8; r++)
#pragma unroll
        for (int c = 0; c < 8; c++) acc[r][c] = 0.f;

    for (int k0 = 0; k0 < 128; k0 += 16) {
        {   // stage A tile: 128x16 = 512 float4, 2 per thread
#pragma unroll
            for (int q = 0; q < 2; q++) {
                int f = tx * 2 + q;
                int r = f >> 2;          // 4 float4 per row
                int c4 = (f & 3) * 4;
                int grow = row0 + r;
                float4 v = make_float4(0.f, 0.f, 0.f, 0.f);
                if (grow < n) v = *(const float4*)(A + (size_t)grow * 128 + k0 + c4);
                As[r][c4 + 0] = v.x; As[r][c4 + 1] = v.y;
                As[r][c4 + 2] = v.z; As[r][c4 + 3] = v.w;
            }
        }
        {   // stage W chunk: 16x128 = 512 float4, 2 per thread
#pragma unroll
            for (int q = 0; q < 2; q++) {
                int f = tx * 2 + q;
                int kr = f >> 5;         // 32 float4 per row
                int c4 = (f & 31) * 4;
                *(float4*)&Ws[kr][c4] = *(const float4*)(W + (size_t)(k0 + kr) * 128 + c4);
            }
        }
        __syncthreads();
#pragma unroll
        for (int kk = 0; kk < 16; kk++) {
            float4 w0 = *(const float4*)&Ws[kk][jg];
            float4 w1 = *(const float4*)&Ws[kk][jg + 4];
            float wv[8] = {w0.x, w0.y, w0.z, w0.w, w1.x, w1.y, w1.z, w1.w};
#pragma unroll
            for (int r = 0; r < 8; r++) {
                float a = As[ig + r][kk];
#pragma unroll
                for (int c = 0; c < 8; c++) acc[r][c] += a * wv[c];
            }
        }
        __syncthreads();
    }

    float bv[8] = {0.f, 0.f, 0.f, 0.f, 0.f, 0.f, 0.f, 0.f};
    if (addb) {
        float4 b0 = *(const float4*)(bias + jg);
        float4 b1 = *(const float4*)(bias + jg + 4);
        bv[0] = b0.x; bv[1] = b0.y; bv[2] = b0.z; bv[3] = b0.w;
        bv[4] = b1.x; bv[5] = b1.y; bv[6] = b1.z; bv[7] = b1.w;
    }
#pragma unroll
    for (int r = 0; r < 8; r++) {
        int grow = row0 + ig + r;
        if (grow < n) {
            float o[8];
#pragma unroll
            for (int c = 0; c < 8; c++) o[c] = acc[r][c] + bv[c];
            *(float4*)(C + (size_t)grow * 128 + jg)     = make_float4(o[0], o[1], o[2], o[3]);
            *(float4*)(C + (size_t)grow * 128 + jg + 4) = make_float4(o[4], o[5], o[6], o[7]);
            if (Cb) {
                float dr = dinv[grow];
                ushort4 u0, u1;
                __hip_bfloat16 t;
                t = __float2bfloat16(o[0] * dr); u0.x = *(unsigned short*)&t;
                t = __float2bfloat16(o[1] * dr); u0.y = *(unsigned short*)&t;
                t = __float2bfloat16(o[2] * dr); u0.z = *(unsigned short*)&t;
                t = __float2bfloat16(o[3] * dr); u0.w = *(unsigned short*)&t;
                t = __float2bfloat16(o[4] * dr); u1.x = *(unsigned short*)&t;
                t = __float2bfloat16(o[5] * dr); u1.y = *(unsigned short*)&t;
                t = __float2bfloat16(o[6] * dr); u1.z = *(unsigned short*)&t;
                t = __float2bfloat16(o[7] * dr); u1.w = *(unsigned short*)&t;
                *(ushort4*)(Cb + (size_t)grow * 128 + jg)     = u0;
                *(ushort4*)(Cb + (size_t)grow * 128 + jg + 4) = u1;
            }
        }
    }
}

// ---------------------------------------------------------------------------
// Fused gather (bf16 pre-scaled) + self-loop(f32) + bias + relu (+ LN).
// ---------------------------------------------------------------------------
template<bool DO_LN>
__global__ __launch_bounds__(256) void agg_post(const float* __restrict__ h,
                                                const unsigned int* __restrict__ hb,
                                                const int* __restrict__ rowPtr,
                                                const int* __restrict__ srcList,
                                                const float* __restrict__ dinv,
                                                const float* __restrict__ b,
                                                const float* __restrict__ g,
                                                const float* __restrict__ beta,
                                                float* __restrict__ out, int n) {
    int wid = (blockIdx.x * 256 + threadIdx.x) >> 6;
    int lane = threadIdx.x & 63;
    if (wid >= n) return;
    int e0 = rowPtr[wid], e1 = rowPtr[wid + 1];
    float dc = dinv[wid];
    size_t base = (size_t)wid * 128 + lane * 2;
    float2 hs = *(const float2*)(h + base);
    float ax = hs.x * dc * dc;
    float ay = hs.y * dc * dc;

    int e = e0;
    for (; e + 8 <= e1; e += 8) {
        int r0 = srcList[e + 0], r1 = srcList[e + 1];
        int r2 = srcList[e + 2], r3 = srcList[e + 3];
        int r4 = srcList[e + 4], r5 = srcList[e + 5];
        int r6 = srcList[e + 6], r7 = srcList[e + 7];
        unsigned int u0 = hb[(size_t)r0 * 64 + lane];
        unsigned int u1 = hb[(size_t)r1 * 64 + lane];
        unsigned int u2 = hb[(size_t)r2 * 64 + lane];
        unsigned int u3 = hb[(size_t)r3 * 64 + lane];
        unsigned int u4 = hb[(size_t)r4 * 64 + lane];
        unsigned int u5 = hb[(size_t)r5 * 64 + lane];
        unsigned int u6 = hb[(size_t)r6 * 64 + lane];
        unsigned int u7 = hb[(size_t)r7 * 64 + lane];
        ax += __uint_as_float(u0 << 16) * dc;  ay += __uint_as_float(u0 & 0xffff0000u) * dc;
        ax += __uint_as_float(u1 << 16) * dc;  ay += __uint_as_float(u1 & 0xffff0000u) * dc;
        ax += __uint_as_float(u2 << 16) * dc;  ay += __uint_as_float(u2 & 0xffff0000u) * dc;
        ax += __uint_as_float(u3 << 16) * dc;  ay += __uint_as_float(u3 & 0xffff0000u) * dc;
        ax += __uint_as_float(u4 << 16) * dc;  ay += __uint_as_float(u4 & 0xffff0000u) * dc;
        ax += __uint_as_float(u5 << 16) * dc;  ay += __uint_as_float(u5 & 0xffff0000u) * dc;
        ax += __uint_as_float(u6 << 16) * dc;  ay += __uint_as_float(u6 & 0xffff0000u) * dc;
        ax += __uint_as_float(u7 << 16) * dc;  ay += __uint_as_float(u7 & 0xffff0000u) * dc;
    }
    for (; e < e1; e++) {
        int r = srcList[e];
        unsigned int u = hb[(size_t)r * 64 + lane];
        ax += __uint_as_float(u << 16) * dc;
        ay += __uint_as_float(u & 0xffff0000u) * dc;
    }

    ax = fmaxf(ax + b[lane * 2 + 0], 0.f);
    ay = fmaxf(ay + b[lane * 2 + 1], 0.f);
    if (DO_LN) {
        float s = ax + ay;
#pragma unroll
        for (int m = 32; m >= 1; m >>= 1) s += __shfl_xor(s, m, 64);
        float mu = s * (1.f / 128.f);
        float dx = ax - mu, dy = ay - mu;
        float sq = dx * dx + dy * dy;
#pragma unroll
        for (int m = 32; m >= 1; m >>= 1) sq += __shfl_xor(sq, m, 64);
        float rs = rsqrtf(sq * (1.f / 128.f) + EPS_LN);
        ax = dx * rs * g[lane * 2 + 0] + beta[lane * 2 + 0];
        ay = dy * rs * g[lane * 2 + 1] + beta[lane * 2 + 1];
    }
    *(float2*)(out + base) = make_float2(ax, ay);
}

// ---------------------------------------------------------------------------
__global__ __launch_bounds__(256) void nhead_f32(const float* __restrict__ hp,
                                                 const float* __restrict__ W,
                                                 const float* __restrict__ b,
                                                 float* __restrict__ out, int n) {
    int i = blockIdx.x * 256 + threadIdx.x;
    if (i >= n) return;
    float p0 = b[0], p1 = b[1], p2 = b[2];
    const float* h = hp + (size_t)i * 128;
    for (int k = 0; k < 128; k++) {
        float v = h[k];
        p0 += v * W[k * 3 + 0];
        p1 += v * W[k * 3 + 1];
        p2 += v * W[k * 3 + 2];
    }
    out[(size_t)i * 3 + 0] = p0;
    out[(size_t)i * 3 + 1] = p1;
    out[(size_t)i * 3 + 2] = p2;
}

// ---------------------------------------------------------------------------
extern "C" void kernel_launch(void* const* d_in, const int* in_sizes, int n_in,
                              void* d_out, int out_size, void* d_ws, size_t ws_size,
                              hipStream_t stream) {
    const float* x   = (const float*)d_in[0];
    const int* ei    = (const int*)d_in[1];
    const float* W1  = (const float*)d_in[2];
    const float* b1  = (const float*)d_in[3];
    const float* W2  = (const float*)d_in[4];
    const float* b2  = (const float*)d_in[5];
    const float* W3  = (const float*)d_in[6];
    const float* b3  = (const float*)d_in[7];
    const float* g1  = (const float*)d_in[8];
    const float* be1 = (const float*)d_in[9];
    const float* g2  = (const float*)d_in[10];
    const float* be2 = (const float*)d_in[11];
    const float* Wp1 = (const float*)d_in[12];
    const float* bp1 = (const float*)d_in[13];
    const float* Wp2 = (const float*)d_in[14];
    const float* bp2 = (const float*)d_in[15];
    float* out = (float*)d_out;

    const int n = in_sizes[0] / 128;   // 50000
    const int E = in_sizes[1] / 2;     // 1600000
    const int* row = ei;
    const int* col = ei + E;

    char* ws = (char*)d_ws;
    size_t nA  = ((size_t)n * 4 + 255) & ~(size_t)255;
    size_t nA1 = ((size_t)(n + 1) * 4 + 255) & ~(size_t)255;
    size_t eA  = ((size_t)E * 4 + 255) & ~(size_t)255;
    size_t hbA = ((size_t)n * 128 * 2 + 255) & ~(size_t)255;
    int*   cnt     = (int*)ws;
    int*   rowPtr  = (int*)(ws + nA);
    int*   cursor  = (int*)(ws + nA + nA1);
    float* dinvp   = (float*)(ws + 2 * nA + nA1);
    int*   partial = (int*)(ws + 3 * nA + nA1);
    int*   srcList = (int*)(ws + 4 * nA + nA1);
    unsigned short* hb = (unsigned short*)(ws + 4 * nA + nA1 + eA);
    float* bufA    = (float*)(ws + 4 * nA + nA1 + eA + hbA);
    float* bufB    = bufA + (size_t)n * 128;

    const int gemmBlocks = (n + 127) / 128;
    const int edgeBlocks = (E + 255) / 256;
    const int nodeWaveBlocks = (n + 3) / 4;
    const int nodeBlocks = (n + 255) / 256;

    const int P = 8;
    const int rw = (n + P - 1) / P;

    // CSR build
    hipMemsetAsync(cnt, 0, (size_t)n * 4, stream);
    count_kernel<<<edgeBlocks, 256, 0, stream>>>(col, cnt, E);
    scan_p1<<<nodeBlocks, 256, 0, stream>>>(cnt, partial, n);
    scan_p2<<<1, 256, 0, stream>>>(partial, rowPtr, n, nodeBlocks);
    scan_p3<<<nodeBlocks, 256, 0, stream>>>(cnt, partial, rowPtr, cursor, dinvp, n);
    fill_part<<<P * edgeBlocks, 256, 0, stream>>>(row, col, cursor, srcList, E,
                                                  edgeBlocks, rw);

    // ---- layer 1 ----
    gemm_nk<<<gemmBlocks, 256, 0, stream>>>(x, W1, b1, dinvp, bufA, hb, n, 0);
    agg_post<true><<<nodeWaveBlocks, 256, 0, stream>>>(bufA, (const unsigned int*)hb,
                                                       rowPtr, srcList, dinvp,
                                                       b1, g1, be1, bufB, n);
    // ---- layer 2 ----
    gemm_nk<<<gemmBlocks, 256, 0, stream>>>(bufB, W2, b2, dinvp, bufA, hb, n, 0);
    agg_post<true><<<nodeWaveBlocks, 256, 0, stream>>>(bufA, (const unsigned int*)hb,
                                                       rowPtr, srcList, dinvp,
                                                       b2, g2, be2, bufB, n);
    // ---- layer 3 (relu, no LN) ----
    gemm_nk<<<gemmBlocks, 256, 0, stream>>>(bufB, W3, b3, dinvp, bufA, hb, n, 0);
    agg_post<false><<<nodeWaveBlocks, 256, 0, stream>>>(bufA, (const unsigned int*)hb,
                                                        rowPtr, srcList, dinvp,
                                                        b3, b3, b3, bufB, n);
    // ---- MLP head ----
    gemm_nk<<<gemmBlocks, 256, 0, stream>>>(bufB, Wp1, bp1, dinvp, bufA, nullptr, n, 1);
    nhead_f32<<<nodeBlocks, 256, 0, stream>>>(bufA, Wp2, bp2, out, n);
}

// Round 19
// 585.971 us; speedup vs baseline: 3.4513x; 1.0205x over previous
//
#include <hip/hip_runtime.h>
#include <hip/hip_bf16.h>

#define EPS_LN 1e-5f

// ===========================================================================
// R19: XCD-pinned CSR build. range = blockIdx % 8 (round-robin XCD heuristic)
// so all stores/atomics of a target-range stay in ONE XCD's L2 -> full-line
// writeback (kills the 13x WRITE amplification) + XCD-local atomics.
// ===========================================================================

// Partitioned degree count: block handles edge chunk (blockIdx>>3), filtered
// to target range (blockIdx&7). cnt atomics stay XCD-local.
__global__ __launch_bounds__(256) void count_part(const int* __restrict__ col,
                                                  int* __restrict__ cnt,
                                                  int E, int rw) {
    int p = blockIdx.x & 7;
    int i = (blockIdx.x >> 3) * 256 + threadIdx.x;
    if (i >= E) return;
    int c = col[i];
    int lo = p * rw;
    if (c >= lo && c < lo + rw) atomicAdd(&cnt[c], 1);
}

__global__ __launch_bounds__(256) void scan_p1(const int* __restrict__ cnt,
                                               int* __restrict__ partial, int n) {
    __shared__ int s[256];
    int t = threadIdx.x;
    int i = blockIdx.x * 256 + t;
    s[t] = (i < n) ? cnt[i] : 0;
    __syncthreads();
    for (int st = 128; st > 0; st >>= 1) {
        if (t < st) s[t] += s[t + st];
        __syncthreads();
    }
    if (t == 0) partial[blockIdx.x] = s[0];
}

__global__ __launch_bounds__(256) void scan_p2(int* __restrict__ partial,
                                               int* __restrict__ rowPtr,
                                               int n, int nb) {
    if (threadIdx.x == 0) {
        int run = 0;
        for (int i = 0; i < nb; i++) { int v = partial[i]; partial[i] = run; run += v; }
        rowPtr[n] = run;
    }
}

__global__ __launch_bounds__(256) void scan_p3(const int* __restrict__ cnt,
                                               const int* __restrict__ partial,
                                               int* __restrict__ rowPtr,
                                               int* __restrict__ cursor,
                                               float* __restrict__ dinv, int n) {
    __shared__ int sh[256];
    int t = threadIdx.x;
    int i = blockIdx.x * 256 + t;
    int v = (i < n) ? cnt[i] : 0;
    sh[t] = v;
    __syncthreads();
    for (int d = 1; d < 256; d <<= 1) {
        int add = (t >= d) ? sh[t - d] : 0;
        __syncthreads();
        sh[t] += add;
        __syncthreads();
    }
    if (i < n) {
        int excl = sh[t] - v + partial[blockIdx.x];
        rowPtr[i] = excl;
        cursor[i] = excl;
        dinv[i] = rsqrtf((float)v + 1.0f);   // +1 self-loop
    }
}

// XCD-pinned fill: range p = blockIdx & 7 -> all srcList writes and cursor
// atomics for range p execute on one XCD.
__global__ __launch_bounds__(256) void fill_part(const int* __restrict__ row,
                                                 const int* __restrict__ col,
                                                 int* __restrict__ cursor,
                                                 int* __restrict__ srcList,
                                                 int E, int rw) {
    int p = blockIdx.x & 7;
    int i = (blockIdx.x >> 3) * 256 + threadIdx.x;
    if (i >= E) return;
    int c = col[i];
    int lo = p * rw;
    if (c >= lo && c < lo + rw) {
        int pos = atomicAdd(&cursor[c], 1);
        srcList[pos] = row[i];
    }
}

// ---------------------------------------------------------------------------
// Tiled GEMM: 128x128 block tile, 256 threads, 8x8 per thread, BK=16.
// ---------------------------------------------------------------------------
__global__ __launch_bounds__(256) void gemm_nk(const float* __restrict__ A,
                                               const float* __restrict__ W,
                                               const float* __restrict__ bias,
                                               const float* __restrict__ dinv,
                                               float* __restrict__ C,
                                               unsigned short* __restrict__ Cb,
                                               int n, int addb) {
    __shared__ float As[128][17];
    __shared__ float Ws[16][128];

    const int tx = threadIdx.x;
    const int row0 = blockIdx.x * 128;
    const int jg = (tx & 15) * 8;
    const int ig = (tx >> 4) * 8;

    float acc[8][8];
#pragma unroll
    for (int r = 0; r < 8; r++)
#pragma unroll
        for (int c = 0; c < 8; c++) acc[r][c] = 0.f;

    for (int k0 = 0; k0 < 128; k0 += 16) {
        {
#pragma unroll
            for (int q = 0; q < 2; q++) {
                int f = tx * 2 + q;
                int r = f >> 2;
                int c4 = (f & 3) * 4;
                int grow = row0 + r;
                float4 v = make_float4(0.f, 0.f, 0.f, 0.f);
                if (grow < n) v = *(const float4*)(A + (size_t)grow * 128 + k0 + c4);
                As[r][c4 + 0] = v.x; As[r][c4 + 1] = v.y;
                As[r][c4 + 2] = v.z; As[r][c4 + 3] = v.w;
            }
        }
        {
#pragma unroll
            for (int q = 0; q < 2; q++) {
                int f = tx * 2 + q;
                int kr = f >> 5;
                int c4 = (f & 31) * 4;
                *(float4*)&Ws[kr][c4] = *(const float4*)(W + (size_t)(k0 + kr) * 128 + c4);
            }
        }
        __syncthreads();
#pragma unroll
        for (int kk = 0; kk < 16; kk++) {
            float4 w0 = *(const float4*)&Ws[kk][jg];
            float4 w1 = *(const float4*)&Ws[kk][jg + 4];
            float wv[8] = {w0.x, w0.y, w0.z, w0.w, w1.x, w1.y, w1.z, w1.w};
#pragma unroll
            for (int r = 0; r < 8; r++) {
                float a = As[ig + r][kk];
#pragma unroll
                for (int c = 0; c < 8; c++) acc[r][c] += a * wv[c];
            }
        }
        __syncthreads();
    }

    float bv[8] = {0.f, 0.f, 0.f, 0.f, 0.f, 0.f, 0.f, 0.f};
    if (addb) {
        float4 b0 = *(const float4*)(bias + jg);
        float4 b1 = *(const float4*)(bias + jg + 4);
        bv[0] = b0.x; bv[1] = b0.y; bv[2] = b0.z; bv[3] = b0.w;
        bv[4] = b1.x; bv[5] = b1.y; bv[6] = b1.z; bv[7] = b1.w;
    }
#pragma unroll
    for (int r = 0; r < 8; r++) {
        int grow = row0 + ig + r;
        if (grow < n) {
            float o[8];
#pragma unroll
            for (int c = 0; c < 8; c++) o[c] = acc[r][c] + bv[c];
            *(float4*)(C + (size_t)grow * 128 + jg)     = make_float4(o[0], o[1], o[2], o[3]);
            *(float4*)(C + (size_t)grow * 128 + jg + 4) = make_float4(o[4], o[5], o[6], o[7]);
            if (Cb) {
                float dr = dinv[grow];
                ushort4 u0, u1;
                __hip_bfloat16 t;
                t = __float2bfloat16(o[0] * dr); u0.x = *(unsigned short*)&t;
                t = __float2bfloat16(o[1] * dr); u0.y = *(unsigned short*)&t;
                t = __float2bfloat16(o[2] * dr); u0.z = *(unsigned short*)&t;
                t = __float2bfloat16(o[3] * dr); u0.w = *(unsigned short*)&t;
                t = __float2bfloat16(o[4] * dr); u1.x = *(unsigned short*)&t;
                t = __float2bfloat16(o[5] * dr); u1.y = *(unsigned short*)&t;
                t = __float2bfloat16(o[6] * dr); u1.z = *(unsigned short*)&t;
                t = __float2bfloat16(o[7] * dr); u1.w = *(unsigned short*)&t;
                *(ushort4*)(Cb + (size_t)grow * 128 + jg)     = u0;
                *(ushort4*)(Cb + (size_t)grow * 128 + jg + 4) = u1;
            }
        }
    }
}

// ---------------------------------------------------------------------------
// Fused gather (bf16 pre-scaled) + self-loop(f32) + bias + relu (+ LN).
// ---------------------------------------------------------------------------
template<bool DO_LN>
__global__ __launch_bounds__(256) void agg_post(const float* __restrict__ h,
                                                const unsigned int* __restrict__ hb,
                                                const int* __restrict__ rowPtr,
                                                const int* __restrict__ srcList,
                                                const float* __restrict__ dinv,
                                                const float* __restrict__ b,
                                                const float* __restrict__ g,
                                                const float* __restrict__ beta,
                                                float* __restrict__ out, int n) {
    int wid = (blockIdx.x * 256 + threadIdx.x) >> 6;
    int lane = threadIdx.x & 63;
    if (wid >= n) return;
    int e0 = rowPtr[wid], e1 = rowPtr[wid + 1];
    float dc = dinv[wid];
    size_t base = (size_t)wid * 128 + lane * 2;
    float2 hs = *(const float2*)(h + base);
    float ax = hs.x * dc * dc;
    float ay = hs.y * dc * dc;

    int e = e0;
    for (; e + 8 <= e1; e += 8) {
        int r0 = srcList[e + 0], r1 = srcList[e + 1];
        int r2 = srcList[e + 2], r3 = srcList[e + 3];
        int r4 = srcList[e + 4], r5 = srcList[e + 5];
        int r6 = srcList[e + 6], r7 = srcList[e + 7];
        unsigned int u0 = hb[(size_t)r0 * 64 + lane];
        unsigned int u1 = hb[(size_t)r1 * 64 + lane];
        unsigned int u2 = hb[(size_t)r2 * 64 + lane];
        unsigned int u3 = hb[(size_t)r3 * 64 + lane];
        unsigned int u4 = hb[(size_t)r4 * 64 + lane];
        unsigned int u5 = hb[(size_t)r5 * 64 + lane];
        unsigned int u6 = hb[(size_t)r6 * 64 + lane];
        unsigned int u7 = hb[(size_t)r7 * 64 + lane];
        ax += __uint_as_float(u0 << 16) * dc;  ay += __uint_as_float(u0 & 0xffff0000u) * dc;
        ax += __uint_as_float(u1 << 16) * dc;  ay += __uint_as_float(u1 & 0xffff0000u) * dc;
        ax += __uint_as_float(u2 << 16) * dc;  ay += __uint_as_float(u2 & 0xffff0000u) * dc;
        ax += __uint_as_float(u3 << 16) * dc;  ay += __uint_as_float(u3 & 0xffff0000u) * dc;
        ax += __uint_as_float(u4 << 16) * dc;  ay += __uint_as_float(u4 & 0xffff0000u) * dc;
        ax += __uint_as_float(u5 << 16) * dc;  ay += __uint_as_float(u5 & 0xffff0000u) * dc;
        ax += __uint_as_float(u6 << 16) * dc;  ay += __uint_as_float(u6 & 0xffff0000u) * dc;
        ax += __uint_as_float(u7 << 16) * dc;  ay += __uint_as_float(u7 & 0xffff0000u) * dc;
    }
    for (; e < e1; e++) {
        int r = srcList[e];
        unsigned int u = hb[(size_t)r * 64 + lane];
        ax += __uint_as_float(u << 16) * dc;
        ay += __uint_as_float(u & 0xffff0000u) * dc;
    }

    ax = fmaxf(ax + b[lane * 2 + 0], 0.f);
    ay = fmaxf(ay + b[lane * 2 + 1], 0.f);
    if (DO_LN) {
        float s = ax + ay;
#pragma unroll
        for (int m = 32; m >= 1; m >>= 1) s += __shfl_xor(s, m, 64);
        float mu = s * (1.f / 128.f);
        float dx = ax - mu, dy = ay - mu;
        float sq = dx * dx + dy * dy;
#pragma unroll
        for (int m = 32; m >= 1; m >>= 1) sq += __shfl_xor(sq, m, 64);
        float rs = rsqrtf(sq * (1.f / 128.f) + EPS_LN);
        ax = dx * rs * g[lane * 2 + 0] + beta[lane * 2 + 0];
        ay = dy * rs * g[lane * 2 + 1] + beta[lane * 2 + 1];
    }
    *(float2*)(out + base) = make_float2(ax, ay);
}

// ---------------------------------------------------------------------------
__global__ __launch_bounds__(256) void nhead_f32(const float* __restrict__ hp,
                                                 const float* __restrict__ W,
                                                 const float* __restrict__ b,
                                                 float* __restrict__ out, int n) {
    int i = blockIdx.x * 256 + threadIdx.x;
    if (i >= n) return;
    float p0 = b[0], p1 = b[1], p2 = b[2];
    const float* h = hp + (size_t)i * 128;
    for (int k = 0; k < 128; k++) {
        float v = h[k];
        p0 += v * W[k * 3 + 0];
        p1 += v * W[k * 3 + 1];
        p2 += v * W[k * 3 + 2];
    }
    out[(size_t)i * 3 + 0] = p0;
    out[(size_t)i * 3 + 1] = p1;
    out[(size_t)i * 3 + 2] = p2;
}

// ---------------------------------------------------------------------------
extern "C" void kernel_launch(void* const* d_in, const int* in_sizes, int n_in,
                              void* d_out, int out_size, void* d_ws, size_t ws_size,
                              hipStream_t stream) {
    const float* x   = (const float*)d_in[0];
    const int* ei    = (const int*)d_in[1];
    const float* W1  = (const float*)d_in[2];
    const float* b1  = (const float*)d_in[3];
    const float* W2  = (const float*)d_in[4];
    const float* b2  = (const float*)d_in[5];
    const float* W3  = (const float*)d_in[6];
    const float* b3  = (const float*)d_in[7];
    const float* g1  = (const float*)d_in[8];
    const float* be1 = (const float*)d_in[9];
    const float* g2  = (const float*)d_in[10];
    const float* be2 = (const float*)d_in[11];
    const float* Wp1 = (const float*)d_in[12];
    const float* bp1 = (const float*)d_in[13];
    const float* Wp2 = (const float*)d_in[14];
    const float* bp2 = (const float*)d_in[15];
    float* out = (float*)d_out;

    const int n = in_sizes[0] / 128;   // 50000
    const int E = in_sizes[1] / 2;     // 1600000
    const int* row = ei;
    const int* col = ei + E;

    char* ws = (char*)d_ws;
    size_t nA  = ((size_t)n * 4 + 255) & ~(size_t)255;
    size_t nA1 = ((size_t)(n + 1) * 4 + 255) & ~(size_t)255;
    size_t eA  = ((size_t)E * 4 + 255) & ~(size_t)255;
    size_t hbA = ((size_t)n * 128 * 2 + 255) & ~(size_t)255;
    int*   cnt     = (int*)ws;
    int*   rowPtr  = (int*)(ws + nA);
    int*   cursor  = (int*)(ws + nA + nA1);
    float* dinvp   = (float*)(ws + 2 * nA + nA1);
    int*   partial = (int*)(ws + 3 * nA + nA1);
    int*   srcList = (int*)(ws + 4 * nA + nA1);
    unsigned short* hb = (unsigned short*)(ws + 4 * nA + nA1 + eA);
    float* bufA    = (float*)(ws + 4 * nA + nA1 + eA + hbA);
    float* bufB    = bufA + (size_t)n * 128;

    const int gemmBlocks = (n + 127) / 128;
    const int edgeBlocks = (E + 255) / 256;
    const int nodeWaveBlocks = (n + 3) / 4;
    const int nodeBlocks = (n + 255) / 256;

    const int P = 8;
    const int rw = (n + P - 1) / P;    // 6250 nodes per XCD-pinned range

    // CSR build (XCD-pinned count + fill)
    hipMemsetAsync(cnt, 0, (size_t)n * 4, stream);
    count_part<<<P * edgeBlocks, 256, 0, stream>>>(col, cnt, E, rw);
    scan_p1<<<nodeBlocks, 256, 0, stream>>>(cnt, partial, n);
    scan_p2<<<1, 256, 0, stream>>>(partial, rowPtr, n, nodeBlocks);
    scan_p3<<<nodeBlocks, 256, 0, stream>>>(cnt, partial, rowPtr, cursor, dinvp, n);
    fill_part<<<P * edgeBlocks, 256, 0, stream>>>(row, col, cursor, srcList, E, rw);

    // ---- layer 1 ----
    gemm_nk<<<gemmBlocks, 256, 0, stream>>>(x, W1, b1, dinvp, bufA, hb, n, 0);
    agg_post<true><<<nodeWaveBlocks, 256, 0, stream>>>(bufA, (const unsigned int*)hb,
                                                       rowPtr, srcList, dinvp,
                                                       b1, g1, be1, bufB, n);
    // ---- layer 2 ----
    gemm_nk<<<gemmBlocks, 256, 0, stream>>>(bufB, W2, b2, dinvp, bufA, hb, n, 0);
    agg_post<true><<<nodeWaveBlocks, 256, 0, stream>>>(bufA, (const unsigned int*)hb,
                                                       rowPtr, srcList, dinvp,
                                                       b2, g2, be2, bufB, n);
    // ---- layer 3 (relu, no LN) ----
    gemm_nk<<<gemmBlocks, 256, 0, stream>>>(bufB, W3, b3, dinvp, bufA, hb, n, 0);
    agg_post<false><<<nodeWaveBlocks, 256, 0, stream>>>(bufA, (const unsigned int*)hb,
                                                        rowPtr, srcList, dinvp,
                                                        b3, b3, b3, bufB, n);
    // ---- MLP head ----
    gemm_nk<<<gemmBlocks, 256, 0, stream>>>(bufB, Wp1, bp1, dinvp, bufA, nullptr, n, 1);
    nhead_f32<<<nodeBlocks, 256, 0, stream>>>(bufA, Wp2, bp2, out, n);
}

// Round 20
// 559.857 us; speedup vs baseline: 3.6123x; 1.0466x over previous
//
#include <hip/hip_runtime.h>
#include <hip/hip_bf16.h>

#define EPS_LN 1e-5f
#define NCAP 51200            // node-capacity for LDS histogram (n = 50000)

// ===========================================================================
// R20: LDS-privatized degree count (paired 16-bit counters, coalesced atomic
// flush) replaces the scattered-atomic count that wrote 50MB for a 200KB
// histogram. Everything else identical to R19.
// ===========================================================================

__global__ __launch_bounds__(256) void count_lds(const int* __restrict__ col,
                                                 int* __restrict__ cnt,
                                                 int E, int n, int nb) {
    __shared__ unsigned int hist[NCAP / 2];   // 2x16-bit counters/word, 100KB
    int t = threadIdx.x;
    for (int i = t; i < NCAP / 2; i += 256) hist[i] = 0;
    __syncthreads();

    int per = (E + nb - 1) / nb;
    int s0 = blockIdx.x * per;
    int s1 = s0 + per; if (s1 > E) s1 = E;
    for (int i = s0 + t; i < s1; i += 256) {
        int c = col[i];
        atomicAdd(&hist[c >> 1], (c & 1) ? 65536u : 1u);
    }
    __syncthreads();

    // coalesced flush, block-staggered start to decorrelate atomic addresses
    int half = (n + 1) >> 1;
    int start = (((size_t)blockIdx.x * half) / nb) & ~(size_t)255;
    for (int j = t; j < half; j += 256) {
        int i = start + j; if (i >= half) i -= half;
        unsigned int v = hist[i];
        if (v) {
            unsigned int lo = v & 0xffffu, hi = v >> 16;
            if (lo) atomicAdd(&cnt[2 * i], (int)lo);
            if (hi && 2 * i + 1 < n) atomicAdd(&cnt[2 * i + 1], (int)hi);
        }
    }
}

__global__ __launch_bounds__(256) void scan_p1(const int* __restrict__ cnt,
                                               int* __restrict__ partial, int n) {
    __shared__ int s[256];
    int t = threadIdx.x;
    int i = blockIdx.x * 256 + t;
    s[t] = (i < n) ? cnt[i] : 0;
    __syncthreads();
    for (int st = 128; st > 0; st >>= 1) {
        if (t < st) s[t] += s[t + st];
        __syncthreads();
    }
    if (t == 0) partial[blockIdx.x] = s[0];
}

__global__ __launch_bounds__(256) void scan_p2(int* __restrict__ partial,
                                               int* __restrict__ rowPtr,
                                               int n, int nb) {
    if (threadIdx.x == 0) {
        int run = 0;
        for (int i = 0; i < nb; i++) { int v = partial[i]; partial[i] = run; run += v; }
        rowPtr[n] = run;
    }
}

__global__ __launch_bounds__(256) void scan_p3(const int* __restrict__ cnt,
                                               const int* __restrict__ partial,
                                               int* __restrict__ rowPtr,
                                               int* __restrict__ cursor,
                                               float* __restrict__ dinv, int n) {
    __shared__ int sh[256];
    int t = threadIdx.x;
    int i = blockIdx.x * 256 + t;
    int v = (i < n) ? cnt[i] : 0;
    sh[t] = v;
    __syncthreads();
    for (int d = 1; d < 256; d <<= 1) {
        int add = (t >= d) ? sh[t - d] : 0;
        __syncthreads();
        sh[t] += add;
        __syncthreads();
    }
    if (i < n) {
        int excl = sh[t] - v + partial[blockIdx.x];
        rowPtr[i] = excl;
        cursor[i] = excl;
        dinv[i] = rsqrtf((float)v + 1.0f);   // +1 self-loop
    }
}

__global__ __launch_bounds__(256) void fill_part(const int* __restrict__ row,
                                                 const int* __restrict__ col,
                                                 int* __restrict__ cursor,
                                                 int* __restrict__ srcList,
                                                 int E, int rw) {
    int p = blockIdx.x & 7;
    int i = (blockIdx.x >> 3) * 256 + threadIdx.x;
    if (i >= E) return;
    int c = col[i];
    int lo = p * rw;
    if (c >= lo && c < lo + rw) {
        int pos = atomicAdd(&cursor[c], 1);
        srcList[pos] = row[i];
    }
}

// ---------------------------------------------------------------------------
// Tiled GEMM: 128x128 block tile, 256 threads, 8x8 per thread, BK=16.
// ---------------------------------------------------------------------------
__global__ __launch_bounds__(256) void gemm_nk(const float* __restrict__ A,
                                               const float* __restrict__ W,
                                               const float* __restrict__ bias,
                                               const float* __restrict__ dinv,
                                               float* __restrict__ C,
                                               unsigned short* __restrict__ Cb,
                                               int n, int addb) {
    __shared__ float As[128][17];
    __shared__ float Ws[16][128];

    const int tx = threadIdx.x;
    const int row0 = blockIdx.x * 128;
    const int jg = (tx & 15) * 8;
    const int ig = (tx >> 4) * 8;

    float acc[8][8];
#pragma unroll
    for (int r = 0; r < 8; r++)
#pragma unroll
        for (int c = 0; c < 8; c++) acc[r][c] = 0.f;

    for (int k0 = 0; k0 < 128; k0 += 16) {
        {
#pragma unroll
            for (int q = 0; q < 2; q++) {
                int f = tx * 2 + q;
                int r = f >> 2;
                int c4 = (f & 3) * 4;
                int grow = row0 + r;
                float4 v = make_float4(0.f, 0.f, 0.f, 0.f);
                if (grow < n) v = *(const float4*)(A + (size_t)grow * 128 + k0 + c4);
                As[r][c4 + 0] = v.x; As[r][c4 + 1] = v.y;
                As[r][c4 + 2] = v.z; As[r][c4 + 3] = v.w;
            }
        }
        {
#pragma unroll
            for (int q = 0; q < 2; q++) {
                int f = tx * 2 + q;
                int kr = f >> 5;
                int c4 = (f & 31) * 4;
                *(float4*)&Ws[kr][c4] = *(const float4*)(W + (size_t)(k0 + kr) * 128 + c4);
            }
        }
        __syncthreads();
#pragma unroll
        for (int kk = 0; kk < 16; kk++) {
            float4 w0 = *(const float4*)&Ws[kk][jg];
            float4 w1 = *(const float4*)&Ws[kk][jg + 4];
            float wv[8] = {w0.x, w0.y, w0.z, w0.w, w1.x, w1.y, w1.z, w1.w};
#pragma unroll
            for (int r = 0; r < 8; r++) {
                float a = As[ig + r][kk];
#pragma unroll
                for (int c = 0; c < 8; c++) acc[r][c] += a * wv[c];
            }
        }
        __syncthreads();
    }

    float bv[8] = {0.f, 0.f, 0.f, 0.f, 0.f, 0.f, 0.f, 0.f};
    if (addb) {
        float4 b0 = *(const float4*)(bias + jg);
        float4 b1 = *(const float4*)(bias + jg + 4);
        bv[0] = b0.x; bv[1] = b0.y; bv[2] = b0.z; bv[3] = b0.w;
        bv[4] = b1.x; bv[5] = b1.y; bv[6] = b1.z; bv[7] = b1.w;
    }
#pragma unroll
    for (int r = 0; r < 8; r++) {
        int grow = row0 + ig + r;
        if (grow < n) {
            float o[8];
#pragma unroll
            for (int c = 0; c < 8; c++) o[c] = acc[r][c] + bv[c];
            *(float4*)(C + (size_t)grow * 128 + jg)     = make_float4(o[0], o[1], o[2], o[3]);
            *(float4*)(C + (size_t)grow * 128 + jg + 4) = make_float4(o[4], o[5], o[6], o[7]);
            if (Cb) {
                float dr = dinv[grow];
                ushort4 u0, u1;
                __hip_bfloat16 t;
                t = __float2bfloat16(o[0] * dr); u0.x = *(unsigned short*)&t;
                t = __float2bfloat16(o[1] * dr); u0.y = *(unsigned short*)&t;
                t = __float2bfloat16(o[2] * dr); u0.z = *(unsigned short*)&t;
                t = __float2bfloat16(o[3] * dr); u0.w = *(unsigned short*)&t;
                t = __float2bfloat16(o[4] * dr); u1.x = *(unsigned short*)&t;
                t = __float2bfloat16(o[5] * dr); u1.y = *(unsigned short*)&t;
                t = __float2bfloat16(o[6] * dr); u1.z = *(unsigned short*)&t;
                t = __float2bfloat16(o[7] * dr); u1.w = *(unsigned short*)&t;
                *(ushort4*)(Cb + (size_t)grow * 128 + jg)     = u0;
                *(ushort4*)(Cb + (size_t)grow * 128 + jg + 4) = u1;
            }
        }
    }
}

// ---------------------------------------------------------------------------
// Fused gather (bf16 pre-scaled) + self-loop(f32) + bias + relu (+ LN).
// ---------------------------------------------------------------------------
template<bool DO_LN>
__global__ __launch_bounds__(256) void agg_post(const float* __restrict__ h,
                                                const unsigned int* __restrict__ hb,
                                                const int* __restrict__ rowPtr,
                                                const int* __restrict__ srcList,
                                                const float* __restrict__ dinv,
                                                const float* __restrict__ b,
                                                const float* __restrict__ g,
                                                const float* __restrict__ beta,
                                                float* __restrict__ out, int n) {
    int wid = (blockIdx.x * 256 + threadIdx.x) >> 6;
    int lane = threadIdx.x & 63;
    if (wid >= n) return;
    int e0 = rowPtr[wid], e1 = rowPtr[wid + 1];
    float dc = dinv[wid];
    size_t base = (size_t)wid * 128 + lane * 2;
    float2 hs = *(const float2*)(h + base);
    float ax = hs.x * dc * dc;
    float ay = hs.y * dc * dc;

    int e = e0;
    for (; e + 8 <= e1; e += 8) {
        int r0 = srcList[e + 0], r1 = srcList[e + 1];
        int r2 = srcList[e + 2], r3 = srcList[e + 3];
        int r4 = srcList[e + 4], r5 = srcList[e + 5];
        int r6 = srcList[e + 6], r7 = srcList[e + 7];
        unsigned int u0 = hb[(size_t)r0 * 64 + lane];
        unsigned int u1 = hb[(size_t)r1 * 64 + lane];
        unsigned int u2 = hb[(size_t)r2 * 64 + lane];
        unsigned int u3 = hb[(size_t)r3 * 64 + lane];
        unsigned int u4 = hb[(size_t)r4 * 64 + lane];
        unsigned int u5 = hb[(size_t)r5 * 64 + lane];
        unsigned int u6 = hb[(size_t)r6 * 64 + lane];
        unsigned int u7 = hb[(size_t)r7 * 64 + lane];
        ax += __uint_as_float(u0 << 16) * dc;  ay += __uint_as_float(u0 & 0xffff0000u) * dc;
        ax += __uint_as_float(u1 << 16) * dc;  ay += __uint_as_float(u1 & 0xffff0000u) * dc;
        ax += __uint_as_float(u2 << 16) * dc;  ay += __uint_as_float(u2 & 0xffff0000u) * dc;
        ax += __uint_as_float(u3 << 16) * dc;  ay += __uint_as_float(u3 & 0xffff0000u) * dc;
        ax += __uint_as_float(u4 << 16) * dc;  ay += __uint_as_float(u4 & 0xffff0000u) * dc;
        ax += __uint_as_float(u5 << 16) * dc;  ay += __uint_as_float(u5 & 0xffff0000u) * dc;
        ax += __uint_as_float(u6 << 16) * dc;  ay += __uint_as_float(u6 & 0xffff0000u) * dc;
        ax += __uint_as_float(u7 << 16) * dc;  ay += __uint_as_float(u7 & 0xffff0000u) * dc;
    }
    for (; e < e1; e++) {
        int r = srcList[e];
        unsigned int u = hb[(size_t)r * 64 + lane];
        ax += __uint_as_float(u << 16) * dc;
        ay += __uint_as_float(u & 0xffff0000u) * dc;
    }

    ax = fmaxf(ax + b[lane * 2 + 0], 0.f);
    ay = fmaxf(ay + b[lane * 2 + 1], 0.f);
    if (DO_LN) {
        float s = ax + ay;
#pragma unroll
        for (int m = 32; m >= 1; m >>= 1) s += __shfl_xor(s, m, 64);
        float mu = s * (1.f / 128.f);
        float dx = ax - mu, dy = ay - mu;
        float sq = dx * dx + dy * dy;
#pragma unroll
        for (int m = 32; m >= 1; m >>= 1) sq += __shfl_xor(sq, m, 64);
        float rs = rsqrtf(sq * (1.f / 128.f) + EPS_LN);
        ax = dx * rs * g[lane * 2 + 0] + beta[lane * 2 + 0];
        ay = dy * rs * g[lane * 2 + 1] + beta[lane * 2 + 1];
    }
    *(float2*)(out + base) = make_float2(ax, ay);
}

// ---------------------------------------------------------------------------
__global__ __launch_bounds__(256) void nhead_f32(const float* __restrict__ hp,
                                                 const float* __restrict__ W,
                                                 const float* __restrict__ b,
                                                 float* __restrict__ out, int n) {
    int i = blockIdx.x * 256 + threadIdx.x;
    if (i >= n) return;
    float p0 = b[0], p1 = b[1], p2 = b[2];
    const float* h = hp + (size_t)i * 128;
    for (int k = 0; k < 128; k++) {
        float v = h[k];
        p0 += v * W[k * 3 + 0];
        p1 += v * W[k * 3 + 1];
        p2 += v * W[k * 3 + 2];
    }
    out[(size_t)i * 3 + 0] = p0;
    out[(size_t)i * 3 + 1] = p1;
    out[(size_t)i * 3 + 2] = p2;
}

// ---------------------------------------------------------------------------
extern "C" void kernel_launch(void* const* d_in, const int* in_sizes, int n_in,
                              void* d_out, int out_size, void* d_ws, size_t ws_size,
                              hipStream_t stream) {
    const float* x   = (const float*)d_in[0];
    const int* ei    = (const int*)d_in[1];
    const float* W1  = (const float*)d_in[2];
    const float* b1  = (const float*)d_in[3];
    const float* W2  = (const float*)d_in[4];
    const float* b2  = (const float*)d_in[5];
    const float* W3  = (const float*)d_in[6];
    const float* b3  = (const float*)d_in[7];
    const float* g1  = (const float*)d_in[8];
    const float* be1 = (const float*)d_in[9];
    const float* g2  = (const float*)d_in[10];
    const float* be2 = (const float*)d_in[11];
    const float* Wp1 = (const float*)d_in[12];
    const float* bp1 = (const float*)d_in[13];
    const float* Wp2 = (const float*)d_in[14];
    const float* bp2 = (const float*)d_in[15];
    float* out = (float*)d_out;

    const int n = in_sizes[0] / 128;   // 50000
    const int E = in_sizes[1] / 2;     // 1600000
    const int* row = ei;
    const int* col = ei + E;

    char* ws = (char*)d_ws;
    size_t nA  = ((size_t)n * 4 + 255) & ~(size_t)255;
    size_t nA1 = ((size_t)(n + 1) * 4 + 255) & ~(size_t)255;
    size_t eA  = ((size_t)E * 4 + 255) & ~(size_t)255;
    size_t hbA = ((size_t)n * 128 * 2 + 255) & ~(size_t)255;
    int*   cnt     = (int*)ws;
    int*   rowPtr  = (int*)(ws + nA);
    int*   cursor  = (int*)(ws + nA + nA1);
    float* dinvp   = (float*)(ws + 2 * nA + nA1);
    int*   partial = (int*)(ws + 3 * nA + nA1);
    int*   srcList = (int*)(ws + 4 * nA + nA1);
    unsigned short* hb = (unsigned short*)(ws + 4 * nA + nA1 + eA);
    float* bufA    = (float*)(ws + 4 * nA + nA1 + eA + hbA);
    float* bufB    = bufA + (size_t)n * 128;

    const int gemmBlocks = (n + 127) / 128;
    const int edgeBlocks = (E + 255) / 256;
    const int nodeWaveBlocks = (n + 3) / 4;
    const int nodeBlocks = (n + 255) / 256;

    const int P = 8;
    const int rw = (n + P - 1) / P;
    const int countBlocks = 128;       // LDS-histogram blocks (1/CU, 100KB LDS)

    // CSR build
    hipMemsetAsync(cnt, 0, (size_t)n * 4, stream);
    count_lds<<<countBlocks, 256, 0, stream>>>(col, cnt, E, n, countBlocks);
    scan_p1<<<nodeBlocks, 256, 0, stream>>>(cnt, partial, n);
    scan_p2<<<1, 256, 0, stream>>>(partial, rowPtr, n, nodeBlocks);
    scan_p3<<<nodeBlocks, 256, 0, stream>>>(cnt, partial, rowPtr, cursor, dinvp, n);
    fill_part<<<P * edgeBlocks, 256, 0, stream>>>(row, col, cursor, srcList, E, rw);

    // ---- layer 1 ----
    gemm_nk<<<gemmBlocks, 256, 0, stream>>>(x, W1, b1, dinvp, bufA, hb, n, 0);
    agg_post<true><<<nodeWaveBlocks, 256, 0, stream>>>(bufA, (const unsigned int*)hb,
                                                       rowPtr, srcList, dinvp,
                                                       b1, g1, be1, bufB, n);
    // ---- layer 2 ----
    gemm_nk<<<gemmBlocks, 256, 0, stream>>>(bufB, W2, b2, dinvp, bufA, hb, n, 0);
    agg_post<true><<<nodeWaveBlocks, 256, 0, stream>>>(bufA, (const unsigned int*)hb,
                                                       rowPtr, srcList, dinvp,
                                                       b2, g2, be2, bufB, n);
    // ---- layer 3 (relu, no LN) ----
    gemm_nk<<<gemmBlocks, 256, 0, stream>>>(bufB, W3, b3, dinvp, bufA, hb, n, 0);
    agg_post<false><<<nodeWaveBlocks, 256, 0, stream>>>(bufA, (const unsigned int*)hb,
                                                        rowPtr, srcList, dinvp,
                                                        b3, b3, b3, bufB, n);
    // ---- MLP head ----
    gemm_nk<<<gemmBlocks, 256, 0, stream>>>(bufB, Wp1, bp1, dinvp, bufA, nullptr, n, 1);
    nhead_f32<<<nodeBlocks, 256, 0, stream>>>(bufA, Wp2, bp2, out, n);
}